// Round 8
// baseline (729.807 us; speedup 1.0000x reference)
//
#include <hip/hip_runtime.h>
#include <hip/hip_cooperative_groups.h>
#include <math.h>

namespace cg = cooperative_groups;

#define NEG_V (-1e30f)
#define SLOPE_V 0.01f
#define EPS_V 1e-5f

typedef __attribute__((ext_vector_type(8))) short bs8;    // 8 bf16 (4 VGPRs)
typedef __attribute__((ext_vector_type(4))) float f32x4;  // mfma acc

// Split fp32 x into bf16 hi + bf16 lo (RNE both). x ≈ hi + lo, rel err ~2^-17.
__device__ __forceinline__ void split2(float x, unsigned short& hi, unsigned short& lo) {
    unsigned u = __float_as_uint(x);
    unsigned h = (u + 0x7FFFu + ((u >> 16) & 1u)) >> 16;
    hi = (unsigned short)h;
    float hf = __uint_as_float(h << 16);
    float l = x - hf;
    unsigned ul = __float_as_uint(l);
    lo = (unsigned short)((ul + 0x7FFFu + ((ul >> 16) & 1u)) >> 16);
}

// ---------------------------------------------------------------------------
// Pure-bf16 split MFMA mainloop (validated rounds 4/6/7).
// ---------------------------------------------------------------------------
__device__ __forceinline__ void mfma_loop(
    const unsigned short* __restrict__ Ahg, const unsigned short* __restrict__ Alg,
    int lda,
    const unsigned short* __restrict__ Bhg, const unsigned short* __restrict__ Blg,
    int ldb, int K, int row0, int col0,
    f32x4 (&acc)[2][2],
    unsigned short (*Ah)[40], unsigned short (*Al)[40],
    unsigned short (*Bh)[40], unsigned short (*Bl)[40])
{
    const int tid = threadIdx.x;
    const int lane = tid & 63, wid = tid >> 6;
    const int wm0 = (wid >> 1) * 32, wn0 = (wid & 1) * 32;
    const int lm = lane & 15, q = lane >> 4;
    const int sr = tid >> 2, sc = (tid & 3) * 8;

    for (int k0 = 0; k0 < K; k0 += 32) {
        *(bs8*)&Ah[sr][sc] = *(const bs8*)(Ahg + (size_t)(row0 + sr) * lda + k0 + sc);
        *(bs8*)&Al[sr][sc] = *(const bs8*)(Alg + (size_t)(row0 + sr) * lda + k0 + sc);
        *(bs8*)&Bh[sr][sc] = *(const bs8*)(Bhg + (size_t)(col0 + sr) * ldb + k0 + sc);
        *(bs8*)&Bl[sr][sc] = *(const bs8*)(Blg + (size_t)(col0 + sr) * ldb + k0 + sc);
        __syncthreads();

        bs8 a_h[2], a_l[2], b_h[2], b_l[2];
#pragma unroll
        for (int t = 0; t < 2; t++) {
            a_h[t] = *(bs8*)&Ah[wm0 + t * 16 + lm][q * 8];
            a_l[t] = *(bs8*)&Al[wm0 + t * 16 + lm][q * 8];
            b_h[t] = *(bs8*)&Bh[wn0 + t * 16 + lm][q * 8];
            b_l[t] = *(bs8*)&Bl[wn0 + t * 16 + lm][q * 8];
        }
#pragma unroll
        for (int mt = 0; mt < 2; mt++)
#pragma unroll
            for (int nt = 0; nt < 2; nt++) {
                acc[mt][nt] = __builtin_amdgcn_mfma_f32_16x16x32_bf16(a_h[mt], b_h[nt], acc[mt][nt], 0, 0, 0);
                acc[mt][nt] = __builtin_amdgcn_mfma_f32_16x16x32_bf16(a_h[mt], b_l[nt], acc[mt][nt], 0, 0, 0);
                acc[mt][nt] = __builtin_amdgcn_mfma_f32_16x16x32_bf16(a_l[mt], b_h[nt], acc[mt][nt], 0, 0, 0);
            }
        __syncthreads();
    }
}

// 64x64 fp32 tile -> transposed bf16 hi/lo (dst[n][k] = src[k][n]).
__device__ __forceinline__ void transpose_split_tile(
    const float* __restrict__ src, int src_ld,
    unsigned short* __restrict__ dh, unsigned short* __restrict__ dl, int dst_ld,
    unsigned short (*Th)[72], unsigned short (*Tl)[72])
{
    int tid = threadIdx.x;
    int r = tid >> 2;
    int cb = (tid & 3) * 16;
#pragma unroll
    for (int cc = 0; cc < 16; cc += 4) {
        float4 v = *(const float4*)(src + (size_t)r * src_ld + cb + cc);
        unsigned short hh, ll;
        split2(v.x, hh, ll); Th[cb + cc + 0][r] = hh; Tl[cb + cc + 0][r] = ll;
        split2(v.y, hh, ll); Th[cb + cc + 1][r] = hh; Tl[cb + cc + 1][r] = ll;
        split2(v.z, hh, ll); Th[cb + cc + 2][r] = hh; Tl[cb + cc + 2][r] = ll;
        split2(v.w, hh, ll); Th[cb + cc + 3][r] = hh; Tl[cb + cc + 3][r] = ll;
    }
    __syncthreads();
    int n = tid >> 2, ch = (tid & 3) * 8;
    *(bs8*)(dh + (size_t)n * dst_ld + ch)      = *(bs8*)&Th[n][ch];
    *(bs8*)(dh + (size_t)n * dst_ld + ch + 32) = *(bs8*)&Th[n][ch + 32];
    *(bs8*)(dl + (size_t)n * dst_ld + ch)      = *(bs8*)&Tl[n][ch];
    *(bs8*)(dl + (size_t)n * dst_ld + ch + 32) = *(bs8*)&Tl[n][ch + 32];
}

// flat fp32 -> split bf16 hi/lo, 4096 elems/job, 16/thread.
__device__ __forceinline__ void flat_split_job(
    const float* __restrict__ src, unsigned short* __restrict__ dh,
    unsigned short* __restrict__ dl, size_t base)
{
    unsigned short hh, ll;
#pragma unroll
    for (int g = 0; g < 2; g++) {
        bs8 sh, sl;
#pragma unroll
        for (int cc = 0; cc < 8; cc += 4) {
            float4 v = *(const float4*)(src + base + g * 8 + cc);
            split2(v.x, hh, ll); sh[cc + 0] = (short)hh; sl[cc + 0] = (short)ll;
            split2(v.y, hh, ll); sh[cc + 1] = (short)hh; sl[cc + 1] = (short)ll;
            split2(v.z, hh, ll); sh[cc + 2] = (short)hh; sl[cc + 2] = (short)ll;
            split2(v.w, hh, ll); sh[cc + 3] = (short)hh; sl[cc + 3] = (short)ll;
        }
        *(bs8*)(dh + base + g * 8) = sh;
        *(bs8*)(dl + base + g * 8) = sl;
    }
}

struct MegaParams {
    const float *feature, *W0, *b0, *W1, *b1, *A1, *ab1, *A2, *ab2, *gamma, *beta;
    const int* adj;
    unsigned short *Wt0h, *Wt0l, *Wt1h, *Wt1l;
    unsigned short *WAth, *WAtl, *fh, *fl, *hth, *htl, *ndh, *ndl, *ph, *pl;
    float *s, *psum, *bA, *node_out, *graph_out;
};

// ---------------------------------------------------------------------------
// Megakernel: 256 blocks x 256 threads, cooperative. Stages wired from the
// round-7 validated kernels. __threadfence() (agent scope -> L2 wb/inv)
// around every grid.sync as insurance against cross-XCD staleness.
// ---------------------------------------------------------------------------
__global__ __launch_bounds__(256, 1) void mega_k(MegaParams P)
{
    cg::grid_group grid = cg::this_grid();
    __shared__ __align__(16) char smem[40960];
    const int bid = blockIdx.x;
    const int tid = threadIdx.x;
    const int lane = tid & 63, wid = tid >> 6;
    const int wm0 = (wid >> 1) * 32, wn0 = (wid & 1) * 32;
    const int lm = lane & 15, q = lane >> 4;

    unsigned short (*sAh)[40] = (unsigned short(*)[40])(smem);
    unsigned short (*sAl)[40] = (unsigned short(*)[40])(smem + 5120);
    unsigned short (*sBh)[40] = (unsigned short(*)[40])(smem + 10240);
    unsigned short (*sBl)[40] = (unsigned short(*)[40])(smem + 15360);

    // ---------------- stage 0: prep (738 jobs) ----------------
    {
        unsigned short (*Th)[72] = (unsigned short(*)[72])(smem);
        unsigned short (*Tl)[72] = (unsigned short(*)[72])(smem + 9216);
        float* A1col = (float*)(smem);             // 768 f (wa jobs)
        float* redb  = (float*)(smem);             // 256 f (bA jobs)
        for (int job = bid; job < 738; job += 256) {
            __syncthreads();
            if (job < 144) {
                int kt = job / 12, nt = job % 12;
                transpose_split_tile(P.W0 + (size_t)(kt * 64) * 768 + nt * 64, 768,
                                     P.Wt0h + (size_t)(nt * 64) * 768 + kt * 64,
                                     P.Wt0l + (size_t)(nt * 64) * 768 + kt * 64, 768, Th, Tl);
            } else if (job < 288) {
                int r = job - 144, kt = r / 12, nt = r % 12;
                transpose_split_tile(P.W1 + (size_t)(kt * 64) * 768 + nt * 64, 768,
                                     P.Wt1h + (size_t)(nt * 64) * 768 + kt * 64,
                                     P.Wt1l + (size_t)(nt * 64) * 768 + kt * 64, 768, Th, Tl);
            } else if (job < 480) {
                flat_split_job(P.feature, P.fh, P.fl,
                               (size_t)(job - 288) * 4096 + tid * 16);
            } else if (job < 736) {
                // wa job: WAt[layer][c][r] = sum_k A1x[k][c] * W[r][k], fp32 exact
                int j2 = job - 480;
                int layer = j2 >> 7, c = j2 & 127;
                const float* W = layer ? P.W1 : P.W0;
                for (int k = tid; k < 768; k += 256) {
                    int row = (c < 64) ? k : 768 + k;
                    A1col[k] = P.A1[(size_t)row * 64 + (c & 63)];
                }
                __syncthreads();
                size_t base = (size_t)layer * 98304 + (size_t)c * 768;
#pragma unroll
                for (int rr = 0; rr < 3; rr++) {
                    int r = tid + rr * 256;
                    const float* wrow = W + (size_t)r * 768;
                    float acc = 0.f;
                    for (int k = 0; k < 768; k += 4) {
                        float4 wv = *(const float4*)(wrow + k);
                        acc = fmaf(A1col[k + 0], wv.x, acc);
                        acc = fmaf(A1col[k + 1], wv.y, acc);
                        acc = fmaf(A1col[k + 2], wv.z, acc);
                        acc = fmaf(A1col[k + 3], wv.w, acc);
                    }
                    unsigned short hv, lv;
                    split2(acc, hv, lv);
                    P.WAth[base + r] = hv;
                    P.WAtl[base + r] = lv;
                }
            } else {
                // bA[layer][c] = sum_k b[k] * A1x[k][c]
                int layer = job - 736;
                const float* bv = layer ? P.b1 : P.b0;
                int c = tid & 127, half = tid >> 7;
                float acc = 0.f;
                for (int kk = 0; kk < 384; kk++) {
                    int k = half * 384 + kk;
                    int row = (c < 64 ? k : 768 + k);
                    acc += bv[k] * P.A1[(size_t)row * 64 + (c & 63)];
                }
                redb[tid] = acc;
                __syncthreads();
                if (tid < 128) P.bA[layer * 128 + tid] = redb[tid] + redb[tid + 128];
            }
        }
    }
    __threadfence(); grid.sync(); __threadfence();

    for (int layer = 0; layer < 2; layer++) {
        const unsigned short* Wth = layer ? P.Wt1h : P.Wt0h;
        const unsigned short* Wtl = layer ? P.Wt1l : P.Wt0l;
        const float* bias = layer ? P.b1 : P.b0;
        const unsigned short* Ahg = layer ? P.ndh : P.fh;
        const unsigned short* Alg = layer ? P.ndl : P.fl;
        const unsigned short* WAthL = P.WAth + (size_t)layer * 98304;
        const unsigned short* WAtlL = P.WAtl + (size_t)layer * 98304;
        const float* bAl = P.bA + layer * 128;

        // ------------- gemm_fused (224 jobs: 14 col x 16 row) -------------
        if (bid < 224) {
            int bx = bid % 14, row0 = (bid / 14) * 64;
            const unsigned short* Bh;
            const unsigned short* Bl;
            int col0;
            if (bx < 12) { Bh = Wth;   Bl = Wtl;   col0 = bx * 64; }
            else         { Bh = WAthL; Bl = WAtlL; col0 = (bx - 12) * 64; }
            f32x4 acc[2][2] = {};
            mfma_loop(Ahg, Alg, 768, Bh, Bl, 768, 768, row0, col0, acc,
                      sAh, sAl, sBh, sBl);
            if (bx >= 12) {
                // s-path: fp32 write (bias added in score)
#pragma unroll
                for (int mt = 0; mt < 2; mt++)
#pragma unroll
                    for (int nt = 0; nt < 2; nt++) {
                        int c = col0 + wn0 + nt * 16 + lm;
#pragma unroll
                        for (int i = 0; i < 4; i++) {
                            int r = row0 + wm0 + mt * 16 + q * 4 + i;
                            P.s[(size_t)r * 128 + c] = acc[mt][nt][i];
                        }
                    }
            } else {
                __syncthreads();
                unsigned short* flat = (unsigned short*)smem;
                unsigned short (*Hi)[69] = (unsigned short(*)[69])flat;
                unsigned short (*Lo)[69] = (unsigned short(*)[69])(flat + 4416);
#pragma unroll
                for (int mt = 0; mt < 2; mt++)
#pragma unroll
                    for (int nt = 0; nt < 2; nt++) {
                        int c = wn0 + nt * 16 + lm;
                        float bv = bias[col0 + c];
#pragma unroll
                        for (int i = 0; i < 4; i++) {
                            int r = wm0 + mt * 16 + q * 4 + i;
                            unsigned short hv, lv;
                            split2(acc[mt][nt][i] + bv, hv, lv);
                            Hi[r][c] = hv; Lo[r][c] = lv;
                        }
                    }
                __syncthreads();
                int d = tid >> 2, kq = (tid & 3) * 16;
                int b = row0 >> 7, kb = row0 & 127;
                bs8 th0, th1, tl0, tl1;
#pragma unroll
                for (int e = 0; e < 8; e++) {
                    th0[e] = Hi[kq + e][d];     th1[e] = Hi[kq + 8 + e][d];
                    tl0[e] = Lo[kq + e][d];     tl1[e] = Lo[kq + 8 + e][d];
                }
                size_t to = ((size_t)b * 768 + col0 + d) * 128 + kb + kq;
                *(bs8*)(P.hth + to) = th0; *(bs8*)(P.hth + to + 8) = th1;
                *(bs8*)(P.htl + to) = tl0; *(bs8*)(P.htl + to + 8) = tl1;
            }
        }
        __threadfence(); grid.sync(); __threadfence();

        // ------------- score (256 jobs: 32 i-tiles x 8 b) -------------
        {
            int bx = bid & 31, b = bid >> 5;
            float (*st)[65] = (float(*)[65])(smem);              // 33280 B
            float (*ss)[65] = (float(*)[65])(smem + 33280);      // 1040 B
            float* a2s  = (float*)(smem + 34320);                // 256 B
            float* warr = (float*)(smem + 34576);                // 16 B
            const int i0 = bx * 4;
            for (int idx = tid; idx < 8192; idx += 256) {
                int j = idx >> 6, h2 = idx & 63;
                st[j][h2] = P.s[(size_t)(b * 128 + j) * 128 + 64 + h2] + bAl[64 + h2];
            }
            {
                int i = tid >> 6, h2 = tid & 63;
                ss[i][h2] = P.s[(size_t)(b * 128 + i0 + i) * 128 + h2] + bAl[h2] + P.ab1[h2];
            }
            if (tid < 64) a2s[tid] = P.A2[tid];
            __syncthreads();
            const float ab2v = P.ab2[0];
            const int rr = tid >> 7;
            const int j = tid & 127;
            const int r0 = rr * 2, r1 = rr * 2 + 1;
            float acc0 = 0.f, acc1 = 0.f;
#pragma unroll 4
            for (int h2 = 0; h2 < 64; h2++) {
                float bb = st[j][h2];
                float cv = a2s[h2];
                acc0 = fmaf(fmaxf(ss[r0][h2] + bb, 0.f), cv, acc0);
                acc1 = fmaf(fmaxf(ss[r1][h2] + bb, 0.f), cv, acc1);
            }
            float e0 = acc0 + ab2v; e0 = (e0 > 0.f) ? e0 : SLOPE_V * e0;
            float e1 = acc1 + ab2v; e1 = (e1 > 0.f) ? e1 : SLOPE_V * e1;
            size_t o0 = (size_t)b * 16384 + (size_t)(i0 + r0) * 128 + j;
            size_t o1 = (size_t)b * 16384 + (size_t)(i0 + r1) * 128 + j;
            float v0 = P.adj[o0] ? expf(e0) : 0.f;
            float v1 = P.adj[o1] ? expf(e1) : 0.f;
            unsigned short hv, lv;
            split2(v0, hv, lv); P.ph[o0] = hv; P.pl[o0] = lv;
            split2(v1, hv, lv); P.ph[o1] = hv; P.pl[o1] = lv;
            float vs = v0 + v1;
#pragma unroll
            for (int o = 32; o > 0; o >>= 1) vs += __shfl_down(vs, o);
            if ((tid & 63) == 0) warr[tid >> 6] = vs;
            __syncthreads();
            if (tid == 0) P.psum[b * 32 + bx] = warr[0] + warr[1] + warr[2] + warr[3];
        }
        __threadfence(); grid.sync(); __threadfence();

        // ------------- attn (192 jobs: 12 col x 2 rowhalf x 8 b) -------------
        if (bid < 192) {
            int col0 = (bid % 12) * 64;
            int row0 = ((bid / 12) & 1) * 64;
            int b = bid / 24;
            float* sred = (float*)(smem + 20480);   // after mfma bufs
            if (tid < 32) sred[tid] = P.psum[b * 32 + tid];
            __syncthreads();
            if (tid == 0) {
                float t = 0.f;
#pragma unroll
                for (int i = 0; i < 32; i++) t += sred[i];
                sred[32] = 1.0f / t;
            }
            __syncthreads();
            float alpha = sred[32];
            f32x4 acc[2][2] = {};
            mfma_loop(P.ph + (size_t)b * 16384, P.pl + (size_t)b * 16384, 128,
                      P.hth + (size_t)b * 98304, P.htl + (size_t)b * 98304, 128, 128,
                      row0, col0, acc, sAh, sAl, sBh, sBl);
            __syncthreads();
            float* C = P.node_out + (size_t)b * 98304;
            unsigned short* flat = (unsigned short*)smem;
            unsigned short (*Hi)[69] = (unsigned short(*)[69])flat;
            unsigned short (*Lo)[69] = (unsigned short(*)[69])(flat + 4416);
#pragma unroll
            for (int mt = 0; mt < 2; mt++)
#pragma unroll
                for (int nt = 0; nt < 2; nt++) {
                    int c = wn0 + nt * 16 + lm;
#pragma unroll
                    for (int i = 0; i < 4; i++) {
                        int r = wm0 + mt * 16 + q * 4 + i;
                        float v = acc[mt][nt][i] * alpha;
                        C[(size_t)(row0 + r) * 768 + col0 + c] = v;
                        unsigned short hv, lv;
                        split2(v, hv, lv);
                        Hi[r][c] = hv; Lo[r][c] = lv;
                    }
                }
            __syncthreads();
            int r = tid >> 2, cq = (tid & 3) * 16;
            bs8 vh0, vh1, vl0, vl1;
#pragma unroll
            for (int e = 0; e < 8; e++) {
                vh0[e] = Hi[r][cq + e];     vh1[e] = Hi[r][cq + 8 + e];
                vl0[e] = Lo[r][cq + e];     vl1[e] = Lo[r][cq + 8 + e];
            }
            size_t ro = (size_t)(b * 128 + row0 + r) * 768 + col0 + cq;
            *(bs8*)(P.ndh + ro) = vh0; *(bs8*)(P.ndh + ro + 8) = vh1;
            *(bs8*)(P.ndl + ro) = vl0; *(bs8*)(P.ndl + ro + 8) = vl1;
        }
        __threadfence(); grid.sync(); __threadfence();
    }

    // ---------------- gsum + batch-norm (24 jobs x 32 cols) ----------------
    if (bid < 24) {
        float (*gbuf)[32] = (float(*)[32])(smem);
        float* mean_s = (float*)(smem + 1024);
        float* inv_s  = (float*)(smem + 1152);
        int bg = tid >> 5, dl = tid & 31;
        int d = bid * 32 + dl;
        float v = 0.f;
        for (int i = 0; i < 128; i++)
            v += P.node_out[(size_t)(bg * 128 + i) * 768 + d];
        gbuf[bg][dl] = v;
        __syncthreads();
        if (tid < 32) {
            float m = 0.f;
#pragma unroll
            for (int b2 = 0; b2 < 8; b2++) m += gbuf[b2][tid];
            m *= 0.125f;
            float var = 0.f;
#pragma unroll
            for (int b2 = 0; b2 < 8; b2++) { float t2 = gbuf[b2][tid] - m; var += t2 * t2; }
            var *= 0.125f;
            mean_s[tid] = m;
            inv_s[tid] = 1.0f / sqrtf(var + EPS_V);
        }
        __syncthreads();
        P.graph_out[bg * 768 + d] =
            P.gamma[d] * (v - mean_s[dl]) * inv_s[dl] + P.beta[d];
    }
}

// ---------------------------------------------------------------------------
extern "C" void kernel_launch(void* const* d_in, const int* in_sizes, int n_in,
                              void* d_out, int out_size, void* d_ws, size_t ws_size,
                              hipStream_t stream)
{
    MegaParams P;
    P.feature = (const float*)d_in[0];
    // d_in[1] = aspect: unused by the reference
    P.adj     = (const int*)d_in[2];
    P.W0      = (const float*)d_in[3];
    P.b0      = (const float*)d_in[4];
    P.W1      = (const float*)d_in[5];
    P.b1      = (const float*)d_in[6];
    P.A1      = (const float*)d_in[7];
    P.ab1     = (const float*)d_in[8];
    P.A2      = (const float*)d_in[9];
    P.ab2     = (const float*)d_in[10];
    P.gamma   = (const float*)d_in[11];
    P.beta    = (const float*)d_in[12];

    float* ws = (float*)d_ws;
    P.s    = ws;                   // 131072 f
    P.psum = ws + 131072;          // 256 f
    P.bA   = ws + 131328;          // 256 f
    unsigned short* u = (unsigned short*)(ws + 131584);  // 16B-aligned
    P.Wt0h = u;                    // 589824 each
    P.Wt0l = P.Wt0h + 589824;
    P.Wt1h = P.Wt0l + 589824;
    P.Wt1l = P.Wt1h + 589824;
    P.WAth = P.Wt1l + 589824;      // 196608 each (2 layers)
    P.WAtl = P.WAth + 196608;
    P.fh   = P.WAtl + 196608;      // 786432 each from here
    P.fl   = P.fh + 786432;
    P.hth  = P.fl + 786432;
    P.htl  = P.hth + 786432;
    P.ndh  = P.htl + 786432;
    P.ndl  = P.ndh + 786432;
    P.ph   = P.ndl + 786432;       // 131072 each
    P.pl   = P.ph + 131072;

    float* out  = (float*)d_out;
    P.graph_out = out;             // (8,768)
    P.node_out  = out + 6144;      // (8,128,768)

    void* args[] = { &P };
    hipLaunchCooperativeKernel((void*)mega_k, dim3(256), dim3(256), args, 0, stream);
}

// Round 9
// 226.024 us; speedup vs baseline: 3.2289x; 3.2289x over previous
//
#include <hip/hip_runtime.h>
#include <math.h>

#define NEG_V (-1e30f)
#define SLOPE_V 0.01f
#define EPS_V 1e-5f

typedef __attribute__((ext_vector_type(8))) short bs8;    // 8 bf16 (4 VGPRs)
typedef __attribute__((ext_vector_type(4))) float f32x4;  // mfma acc

// Split fp32 x into bf16 hi + bf16 lo (RNE both). x ≈ hi + lo, rel err ~2^-17.
__device__ __forceinline__ void split2(float x, unsigned short& hi, unsigned short& lo) {
    unsigned u = __float_as_uint(x);
    unsigned h = (u + 0x7FFFu + ((u >> 16) & 1u)) >> 16;
    hi = (unsigned short)h;
    float hf = __uint_as_float(h << 16);
    float l = x - hf;
    unsigned ul = __float_as_uint(l);
    lo = (unsigned short)((ul + 0x7FFFu + ((ul >> 16) & 1u)) >> 16);
}

// ---------------------------------------------------------------------------
// Pure-bf16 split MFMA mainloop (validated rounds 4/6/7). 256 thr, tile
// 64x64, wave tile 32x32, 3 mfma per tile (hh, hl, lh). A row-major split
// [M][K]; B transposed split Bt[n][k]. LDS rows padded to 40 bf16.
// ---------------------------------------------------------------------------
__device__ __forceinline__ void mfma_loop(
    const unsigned short* __restrict__ Ahg, const unsigned short* __restrict__ Alg,
    int lda,
    const unsigned short* __restrict__ Bhg, const unsigned short* __restrict__ Blg,
    int ldb, int K, int row0, int col0,
    f32x4 (&acc)[2][2],
    unsigned short (*Ah)[40], unsigned short (*Al)[40],
    unsigned short (*Bh)[40], unsigned short (*Bl)[40])
{
    const int tid = threadIdx.x;
    const int lane = tid & 63, wid = tid >> 6;
    const int wm0 = (wid >> 1) * 32, wn0 = (wid & 1) * 32;
    const int lm = lane & 15, q = lane >> 4;
    const int sr = tid >> 2, sc = (tid & 3) * 8;

    for (int k0 = 0; k0 < K; k0 += 32) {
        *(bs8*)&Ah[sr][sc] = *(const bs8*)(Ahg + (size_t)(row0 + sr) * lda + k0 + sc);
        *(bs8*)&Al[sr][sc] = *(const bs8*)(Alg + (size_t)(row0 + sr) * lda + k0 + sc);
        *(bs8*)&Bh[sr][sc] = *(const bs8*)(Bhg + (size_t)(col0 + sr) * ldb + k0 + sc);
        *(bs8*)&Bl[sr][sc] = *(const bs8*)(Blg + (size_t)(col0 + sr) * ldb + k0 + sc);
        __syncthreads();

        bs8 a_h[2], a_l[2], b_h[2], b_l[2];
#pragma unroll
        for (int t = 0; t < 2; t++) {
            a_h[t] = *(bs8*)&Ah[wm0 + t * 16 + lm][q * 8];
            a_l[t] = *(bs8*)&Al[wm0 + t * 16 + lm][q * 8];
            b_h[t] = *(bs8*)&Bh[wn0 + t * 16 + lm][q * 8];
            b_l[t] = *(bs8*)&Bl[wn0 + t * 16 + lm][q * 8];
        }
#pragma unroll
        for (int mt = 0; mt < 2; mt++)
#pragma unroll
            for (int nt = 0; nt < 2; nt++) {
                acc[mt][nt] = __builtin_amdgcn_mfma_f32_16x16x32_bf16(a_h[mt], b_h[nt], acc[mt][nt], 0, 0, 0);
                acc[mt][nt] = __builtin_amdgcn_mfma_f32_16x16x32_bf16(a_h[mt], b_l[nt], acc[mt][nt], 0, 0, 0);
                acc[mt][nt] = __builtin_amdgcn_mfma_f32_16x16x32_bf16(a_l[mt], b_h[nt], acc[mt][nt], 0, 0, 0);
            }
        __syncthreads();
    }
}

// 64x64 fp32 tile -> transposed bf16 hi/lo (dst[n][k] = src[k][n]).
__device__ __forceinline__ void transpose_split_tile(
    const float* __restrict__ src, int src_ld,
    unsigned short* __restrict__ dh, unsigned short* __restrict__ dl, int dst_ld,
    unsigned short (*Th)[72], unsigned short (*Tl)[72])
{
    int tid = threadIdx.x;
    int r = tid >> 2;
    int cb = (tid & 3) * 16;
#pragma unroll
    for (int cc = 0; cc < 16; cc += 4) {
        float4 v = *(const float4*)(src + (size_t)r * src_ld + cb + cc);
        unsigned short hh, ll;
        split2(v.x, hh, ll); Th[cb + cc + 0][r] = hh; Tl[cb + cc + 0][r] = ll;
        split2(v.y, hh, ll); Th[cb + cc + 1][r] = hh; Tl[cb + cc + 1][r] = ll;
        split2(v.z, hh, ll); Th[cb + cc + 2][r] = hh; Tl[cb + cc + 2][r] = ll;
        split2(v.w, hh, ll); Th[cb + cc + 3][r] = hh; Tl[cb + cc + 3][r] = ll;
    }
    __syncthreads();
    int n = tid >> 2, ch = (tid & 3) * 8;
    *(bs8*)(dh + (size_t)n * dst_ld + ch)      = *(bs8*)&Th[n][ch];
    *(bs8*)(dh + (size_t)n * dst_ld + ch + 32) = *(bs8*)&Th[n][ch + 32];
    *(bs8*)(dl + (size_t)n * dst_ld + ch)      = *(bs8*)&Tl[n][ch];
    *(bs8*)(dl + (size_t)n * dst_ld + ch + 32) = *(bs8*)&Tl[n][ch + 32];
}

// flat fp32 -> split bf16 hi/lo, 4096 elems/job, 16/thread.
__device__ __forceinline__ void flat_split_job(
    const float* __restrict__ src, unsigned short* __restrict__ dh,
    unsigned short* __restrict__ dl, size_t base)
{
    unsigned short hh, ll;
#pragma unroll
    for (int g = 0; g < 2; g++) {
        bs8 sh, sl;
#pragma unroll
        for (int cc = 0; cc < 8; cc += 4) {
            float4 v = *(const float4*)(src + base + g * 8 + cc);
            split2(v.x, hh, ll); sh[cc + 0] = (short)hh; sl[cc + 0] = (short)ll;
            split2(v.y, hh, ll); sh[cc + 1] = (short)hh; sl[cc + 1] = (short)ll;
            split2(v.z, hh, ll); sh[cc + 2] = (short)hh; sl[cc + 2] = (short)ll;
            split2(v.w, hh, ll); sh[cc + 3] = (short)hh; sl[cc + 3] = (short)ll;
        }
        *(bs8*)(dh + base + g * 8) = sh;
        *(bs8*)(dl + base + g * 8) = sl;
    }
}

// ---------------------------------------------------------------------------
// Prep, grid 738, one job per block:
//   [0,144)   W0 -> Wt0 transposed split
//   [144,288) W1 -> Wt1 transposed split
//   [288,480) feature -> fh/fl row-major split
//   [480,736) WA direct fp32: WAt[layer][c][r] = sum_k A1x[k][c] * W[r][k]
//             (validated in round 8's mega; split to bf16 hi/lo on store)
//   [736,738) bA[layer][c] = sum_k b[k] * A1x[k][c]
// ---------------------------------------------------------------------------
__global__ __launch_bounds__(256) void prep_k(
    const float* __restrict__ W0, const float* __restrict__ W1,
    const float* __restrict__ A1, const float* __restrict__ feature,
    const float* __restrict__ b0, const float* __restrict__ b1,
    unsigned short* Wt0h, unsigned short* Wt0l,
    unsigned short* Wt1h, unsigned short* Wt1l,
    unsigned short* fh, unsigned short* fl,
    unsigned short* WAth, unsigned short* WAtl,
    float* bA)
{
    __shared__ __align__(16) char smem[20480];
    int id = blockIdx.x, tid = threadIdx.x;
    if (id < 288) {
        unsigned short (*Th)[72] = (unsigned short(*)[72])(smem);
        unsigned short (*Tl)[72] = (unsigned short(*)[72])(smem + 9216);
        if (id < 144) {
            int kt = id / 12, nt = id % 12;
            transpose_split_tile(W0 + (size_t)(kt * 64) * 768 + nt * 64, 768,
                                 Wt0h + (size_t)(nt * 64) * 768 + kt * 64,
                                 Wt0l + (size_t)(nt * 64) * 768 + kt * 64, 768, Th, Tl);
        } else {
            int r = id - 144, kt = r / 12, nt = r % 12;
            transpose_split_tile(W1 + (size_t)(kt * 64) * 768 + nt * 64, 768,
                                 Wt1h + (size_t)(nt * 64) * 768 + kt * 64,
                                 Wt1l + (size_t)(nt * 64) * 768 + kt * 64, 768, Th, Tl);
        }
    } else if (id < 480) {
        flat_split_job(feature, fh, fl, (size_t)(id - 288) * 4096 + tid * 16);
    } else if (id < 736) {
        // WA direct: one output column c (768 values) per block, fp32 exact.
        float* A1col = (float*)(smem);   // 768 f
        int j2 = id - 480;
        int layer = j2 >> 7, c = j2 & 127;
        const float* W = layer ? W1 : W0;
        for (int k = tid; k < 768; k += 256) {
            int row = (c < 64) ? k : 768 + k;
            A1col[k] = A1[(size_t)row * 64 + (c & 63)];
        }
        __syncthreads();
        size_t base = (size_t)layer * 98304 + (size_t)c * 768;
#pragma unroll
        for (int rr = 0; rr < 3; rr++) {
            int r = tid + rr * 256;
            const float* wrow = W + (size_t)r * 768;
            float acc = 0.f;
            for (int k = 0; k < 768; k += 4) {
                float4 wv = *(const float4*)(wrow + k);
                acc = fmaf(A1col[k + 0], wv.x, acc);
                acc = fmaf(A1col[k + 1], wv.y, acc);
                acc = fmaf(A1col[k + 2], wv.z, acc);
                acc = fmaf(A1col[k + 3], wv.w, acc);
            }
            unsigned short hv, lv;
            split2(acc, hv, lv);
            WAth[base + r] = hv;
            WAtl[base + r] = lv;
        }
    } else {
        float* redb = (float*)(smem);    // 256 f
        int layer = id - 736;
        const float* bv = layer ? b1 : b0;
        int c = tid & 127, half = tid >> 7;
        float acc = 0.f;
        for (int kk = 0; kk < 384; kk++) {
            int k = half * 384 + kk;
            int row = (c < 64 ? k : 768 + k);
            acc += bv[k] * A1[(size_t)row * 64 + (c & 63)];
        }
        redb[tid] = acc;
        __syncthreads();
        if (tid < 128) bA[layer * 128 + tid] = redb[tid] + redb[tid + 128];
    }
}

// ---------------------------------------------------------------------------
// Fused gemm: grid (14, 16). col-tiles 0-11: h = A@W + bias -> transposed
// split hth/htl (attn B). col-tiles 12-13: s = A@WA -> fp32 (bias in score).
// (validated round 7)
// ---------------------------------------------------------------------------
__global__ __launch_bounds__(256) void gemm_fused_k(
    const unsigned short* __restrict__ Ahg, const unsigned short* __restrict__ Alg,
    const unsigned short* __restrict__ Wth, const unsigned short* __restrict__ Wtl,
    const unsigned short* __restrict__ WAth, const unsigned short* __restrict__ WAtl,
    const float* __restrict__ bias,
    unsigned short* __restrict__ hth, unsigned short* __restrict__ htl,
    float* __restrict__ s)
{
    __shared__ unsigned short smem[4][64][40];
    int bx = blockIdx.x, row0 = blockIdx.y * 64;
    const unsigned short* Bh;
    const unsigned short* Bl;
    int col0;
    if (bx < 12) { Bh = Wth;  Bl = Wtl;  col0 = bx * 64; }
    else         { Bh = WAth; Bl = WAtl; col0 = (bx - 12) * 64; }
    f32x4 acc[2][2] = {};
    mfma_loop(Ahg, Alg, 768, Bh, Bl, 768, 768, row0, col0, acc,
              smem[0], smem[1], smem[2], smem[3]);
    int tid = threadIdx.x, lane = tid & 63, wid = tid >> 6;
    int wm0 = (wid >> 1) * 32, wn0 = (wid & 1) * 32;
    int lm = lane & 15, q = lane >> 4;
    if (bx >= 12) {
#pragma unroll
        for (int mt = 0; mt < 2; mt++)
#pragma unroll
            for (int nt = 0; nt < 2; nt++) {
                int c = col0 + wn0 + nt * 16 + lm;
#pragma unroll
                for (int i = 0; i < 4; i++) {
                    int r = row0 + wm0 + mt * 16 + q * 4 + i;
                    s[(size_t)r * 128 + c] = acc[mt][nt][i];
                }
            }
        return;
    }
    __syncthreads();
    unsigned short* flat = &smem[0][0][0];
    unsigned short (*Hi)[69] = (unsigned short(*)[69])flat;
    unsigned short (*Lo)[69] = (unsigned short(*)[69])(flat + 4416);
#pragma unroll
    for (int mt = 0; mt < 2; mt++)
#pragma unroll
        for (int nt = 0; nt < 2; nt++) {
            int c = wn0 + nt * 16 + lm;
            float bv = bias[col0 + c];
#pragma unroll
            for (int i = 0; i < 4; i++) {
                int r = wm0 + mt * 16 + q * 4 + i;
                unsigned short hv, lv;
                split2(acc[mt][nt][i] + bv, hv, lv);
                Hi[r][c] = hv; Lo[r][c] = lv;
            }
        }
    __syncthreads();
    int d = tid >> 2, kq = (tid & 3) * 16;
    int b = row0 >> 7, kb = row0 & 127;
    bs8 th0, th1, tl0, tl1;
#pragma unroll
    for (int e = 0; e < 8; e++) {
        th0[e] = Hi[kq + e][d];     th1[e] = Hi[kq + 8 + e][d];
        tl0[e] = Lo[kq + e][d];     tl1[e] = Lo[kq + 8 + e][d];
    }
    size_t to = ((size_t)b * 768 + col0 + d) * 128 + kb + kq;
    *(bs8*)(hth + to) = th0; *(bs8*)(hth + to + 8) = th1;
    *(bs8*)(htl + to) = tl0; *(bs8*)(htl + to + 8) = tl1;
}

// ---------------------------------------------------------------------------
// score_k: masked score + exp (no max-shift; |e|<<80 by construction, masked
// entries = 0 exactly). Writes split exp to ph/pl + per-block sum psum[b][32].
// grid (32 i-tiles, 8 b), block 256. (validated round 7)
// ---------------------------------------------------------------------------
__global__ __launch_bounds__(256) void score_k(
    const float* __restrict__ s, const int* __restrict__ adj,
    const float* __restrict__ ab1, const float* __restrict__ A2,
    const float* __restrict__ ab2, const float* __restrict__ bA,
    unsigned short* __restrict__ ph, unsigned short* __restrict__ pl,
    float* __restrict__ psum)
{
    __shared__ float st[128][65];
    __shared__ float ss[4][65];
    __shared__ float a2s[64];
    __shared__ float warr[4];
    const int bx = blockIdx.x, b = blockIdx.y, tid = threadIdx.x;
    const int i0 = bx * 4;
    for (int idx = tid; idx < 8192; idx += 256) {
        int j = idx >> 6, h2 = idx & 63;
        st[j][h2] = s[(size_t)(b * 128 + j) * 128 + 64 + h2] + bA[64 + h2];
    }
    {
        int i = tid >> 6, h2 = tid & 63;
        ss[i][h2] = s[(size_t)(b * 128 + i0 + i) * 128 + h2] + bA[h2] + ab1[h2];
    }
    if (tid < 64) a2s[tid] = A2[tid];
    __syncthreads();
    const float ab2v = ab2[0];
    const int rr = tid >> 7;
    const int j = tid & 127;
    const int r0 = rr * 2, r1 = rr * 2 + 1;
    float acc0 = 0.f, acc1 = 0.f;
#pragma unroll 4
    for (int h2 = 0; h2 < 64; h2++) {
        float bb = st[j][h2];
        float cv = a2s[h2];
        acc0 = fmaf(fmaxf(ss[r0][h2] + bb, 0.f), cv, acc0);
        acc1 = fmaf(fmaxf(ss[r1][h2] + bb, 0.f), cv, acc1);
    }
    float e0 = acc0 + ab2v; e0 = (e0 > 0.f) ? e0 : SLOPE_V * e0;
    float e1 = acc1 + ab2v; e1 = (e1 > 0.f) ? e1 : SLOPE_V * e1;
    size_t o0 = (size_t)b * 16384 + (size_t)(i0 + r0) * 128 + j;
    size_t o1 = (size_t)b * 16384 + (size_t)(i0 + r1) * 128 + j;
    float v0 = adj[o0] ? expf(e0) : 0.f;
    float v1 = adj[o1] ? expf(e1) : 0.f;
    unsigned short hv, lv;
    split2(v0, hv, lv); ph[o0] = hv; pl[o0] = lv;
    split2(v1, hv, lv); ph[o1] = hv; pl[o1] = lv;
    float vs = v0 + v1;
#pragma unroll
    for (int o = 32; o > 0; o >>= 1) vs += __shfl_down(vs, o);
    if ((tid & 63) == 0) warr[tid >> 6] = vs;
    __syncthreads();
    if (tid == 0) psum[b * 32 + bx] = warr[0] + warr[1] + warr[2] + warr[3];
}

// ---------------------------------------------------------------------------
// attn: node[b] = (1/sum_b) * P[b] @ h[b]; alpha from psum partials.
// Outputs fp32 node AND split ndh/ndl. grid (12,2,8). (validated round 7)
// ---------------------------------------------------------------------------
__global__ __launch_bounds__(256) void attn_mfma_k(
    const unsigned short* __restrict__ ph, const unsigned short* __restrict__ pl,
    const unsigned short* __restrict__ hth, const unsigned short* __restrict__ htl,
    const float* __restrict__ psum, float* __restrict__ node,
    unsigned short* __restrict__ nodeh, unsigned short* __restrict__ nodel)
{
    __shared__ unsigned short smem[4][64][40];
    __shared__ float sred[33];
    int b = blockIdx.z;
    int row0 = blockIdx.y * 64, col0 = blockIdx.x * 64;
    int tid = threadIdx.x;
    if (tid < 32) sred[tid] = psum[b * 32 + tid];
    __syncthreads();
    if (tid == 0) {
        float t = 0.f;
#pragma unroll
        for (int i = 0; i < 32; i++) t += sred[i];
        sred[32] = 1.0f / t;
    }
    __syncthreads();
    float alpha = sred[32];
    f32x4 acc[2][2] = {};
    mfma_loop(ph + (size_t)b * 16384, pl + (size_t)b * 16384, 128,
              hth + (size_t)b * 98304, htl + (size_t)b * 98304, 128, 128,
              row0, col0, acc, smem[0], smem[1], smem[2], smem[3]);
    __syncthreads();
    float* C = node + (size_t)b * 98304;
    unsigned short* flat = &smem[0][0][0];
    unsigned short (*Hi)[69] = (unsigned short(*)[69])flat;
    unsigned short (*Lo)[69] = (unsigned short(*)[69])(flat + 4416);
    int lane = tid & 63, wid = tid >> 6;
    int wm0 = (wid >> 1) * 32, wn0 = (wid & 1) * 32;
    int lm = lane & 15, q = lane >> 4;
#pragma unroll
    for (int mt = 0; mt < 2; mt++)
#pragma unroll
        for (int nt = 0; nt < 2; nt++) {
            int c = wn0 + nt * 16 + lm;
#pragma unroll
            for (int i = 0; i < 4; i++) {
                int r = wm0 + mt * 16 + q * 4 + i;
                float v = acc[mt][nt][i] * alpha;
                C[(size_t)(row0 + r) * 768 + col0 + c] = v;
                unsigned short hv, lv;
                split2(v, hv, lv);
                Hi[r][c] = hv; Lo[r][c] = lv;
            }
        }
    __syncthreads();
    int r = tid >> 2, cq = (tid & 3) * 16;
    bs8 vh0, vh1, vl0, vl1;
#pragma unroll
    for (int e = 0; e < 8; e++) {
        vh0[e] = Hi[r][cq + e];     vh1[e] = Hi[r][cq + 8 + e];
        vl0[e] = Lo[r][cq + e];     vl1[e] = Lo[r][cq + 8 + e];
    }
    size_t ro = (size_t)(b * 128 + row0 + r) * 768 + col0 + cq;
    *(bs8*)(nodeh + ro) = vh0; *(bs8*)(nodeh + ro + 8) = vh1;
    *(bs8*)(nodel + ro) = vl0; *(bs8*)(nodel + ro + 8) = vl1;
}

// ---------------------------------------------------------------------------
// Fused graph-sum + batch-norm. grid 12, block 512. (validated round 4)
// ---------------------------------------------------------------------------
__global__ __launch_bounds__(512) void gsum_bnorm_k(
    const float* __restrict__ node, const float* __restrict__ gamma,
    const float* __restrict__ beta, float* __restrict__ out)
{
    __shared__ float gbuf[8][64];
    __shared__ float mean_s[64], inv_s[64];
    int tid = threadIdx.x;
    int bg = tid >> 6, dl = tid & 63;
    int d = blockIdx.x * 64 + dl;
    float v = 0.f;
    for (int i = 0; i < 128; i++)
        v += node[(size_t)(bg * 128 + i) * 768 + d];
    gbuf[bg][dl] = v;
    __syncthreads();
    if (tid < 64) {
        float m = 0.f;
#pragma unroll
        for (int b = 0; b < 8; b++) m += gbuf[b][tid];
        m *= 0.125f;
        float var = 0.f;
#pragma unroll
        for (int b = 0; b < 8; b++) { float t = gbuf[b][tid] - m; var += t * t; }
        var *= 0.125f;
        mean_s[tid] = m;
        inv_s[tid] = 1.0f / sqrtf(var + EPS_V);
    }
    __syncthreads();
    out[bg * 768 + d] = gamma[d] * (v - mean_s[dl]) * inv_s[dl] + beta[d];
}

// ---------------------------------------------------------------------------
extern "C" void kernel_launch(void* const* d_in, const int* in_sizes, int n_in,
                              void* d_out, int out_size, void* d_ws, size_t ws_size,
                              hipStream_t stream)
{
    const float* feature = (const float*)d_in[0];
    // d_in[1] = aspect: unused by the reference
    const int*   adj     = (const int*)d_in[2];
    const float* W0      = (const float*)d_in[3];
    const float* b0      = (const float*)d_in[4];
    const float* W1      = (const float*)d_in[5];
    const float* b1      = (const float*)d_in[6];
    const float* A1      = (const float*)d_in[7];
    const float* ab1     = (const float*)d_in[8];
    const float* A2      = (const float*)d_in[9];
    const float* ab2     = (const float*)d_in[10];
    const float* gamma   = (const float*)d_in[11];
    const float* beta    = (const float*)d_in[12];

    float* ws    = (float*)d_ws;
    float* s     = ws;               // 131072
    float* psum  = ws + 131072;      // 256
    float* bA    = ws + 131328;      // 256
    unsigned short* u = (unsigned short*)(ws + 131584);  // 16B-aligned
    unsigned short* Wt0h = u;                    // 589824 each
    unsigned short* Wt0l = Wt0h + 589824;
    unsigned short* Wt1h = Wt0l + 589824;
    unsigned short* Wt1l = Wt1h + 589824;
    unsigned short* WAth = Wt1l + 589824;        // 196608 each (2 layers)
    unsigned short* WAtl = WAth + 196608;
    unsigned short* fh   = WAtl + 196608;        // 786432 each from here
    unsigned short* fl   = fh + 786432;
    unsigned short* hth  = fl + 786432;
    unsigned short* htl  = hth + 786432;
    unsigned short* ndh  = htl + 786432;
    unsigned short* ndl  = ndh + 786432;
    unsigned short* ph   = ndl + 786432;         // 131072 each
    unsigned short* pl   = ph + 131072;

    float* out       = (float*)d_out;
    float* graph_out = out;          // (8,768)
    float* node_out  = out + 6144;   // (8,128,768)

    prep_k<<<738, 256, 0, stream>>>(W0, W1, A1, feature, b0, b1,
                                    Wt0h, Wt0l, Wt1h, Wt1l,
                                    fh, fl, WAth, WAtl, bA);

    for (int layer = 0; layer < 2; layer++) {
        const unsigned short* Wth = layer ? Wt1h : Wt0h;
        const unsigned short* Wtl = layer ? Wt1l : Wt0l;
        const float* bb = layer ? b1 : b0;
        const unsigned short* Ahg = layer ? ndh : fh;
        const unsigned short* Alg = layer ? ndl : fl;
        gemm_fused_k<<<dim3(14, 16), 256, 0, stream>>>(
            Ahg, Alg, Wth, Wtl, WAth + (size_t)layer * 98304,
            WAtl + (size_t)layer * 98304, bb, hth, htl, s);
        score_k<<<dim3(32, 8), 256, 0, stream>>>(s, adj, ab1, A2, ab2,
                                                 bA + layer * 128, ph, pl, psum);
        attn_mfma_k<<<dim3(12, 2, 8), 256, 0, stream>>>(ph, pl, hth, htl, psum,
                                                        node_out, ndh, ndl);
    }
    gsum_bnorm_k<<<12, 512, 0, stream>>>(node_out, gamma, beta, graph_out);
}

// Round 10
// 181.636 us; speedup vs baseline: 4.0180x; 1.2444x over previous
//
#include <hip/hip_runtime.h>
#include <math.h>

#define NEG_V (-1e30f)
#define SLOPE_V 0.01f
#define EPS_V 1e-5f

typedef __attribute__((ext_vector_type(8))) short bs8;    // 8 bf16 (4 VGPRs)
typedef __attribute__((ext_vector_type(4))) float f32x4;  // mfma acc

// Split fp32 x into bf16 hi + bf16 lo (RNE both). x ≈ hi + lo, rel err ~2^-17.
__device__ __forceinline__ void split2(float x, unsigned short& hi, unsigned short& lo) {
    unsigned u = __float_as_uint(x);
    unsigned h = (u + 0x7FFFu + ((u >> 16) & 1u)) >> 16;
    hi = (unsigned short)h;
    float hf = __uint_as_float(h << 16);
    float l = x - hf;
    unsigned ul = __float_as_uint(l);
    lo = (unsigned short)((ul + 0x7FFFu + ((ul >> 16) & 1u)) >> 16);
}

// ---------------------------------------------------------------------------
// Pure-bf16 split MFMA mainloop (validated rounds 4/6/7). 256 thr, tile
// 64x64, wave tile 32x32, 3 mfma per tile (hh, hl, lh). A row-major split
// [M][K]; B transposed split Bt[n][k]. LDS rows padded to 40 bf16.
// ---------------------------------------------------------------------------
__device__ __forceinline__ void mfma_loop(
    const unsigned short* __restrict__ Ahg, const unsigned short* __restrict__ Alg,
    int lda,
    const unsigned short* __restrict__ Bhg, const unsigned short* __restrict__ Blg,
    int ldb, int K, int row0, int col0,
    f32x4 (&acc)[2][2],
    unsigned short (*Ah)[40], unsigned short (*Al)[40],
    unsigned short (*Bh)[40], unsigned short (*Bl)[40])
{
    const int tid = threadIdx.x;
    const int lane = tid & 63, wid = tid >> 6;
    const int wm0 = (wid >> 1) * 32, wn0 = (wid & 1) * 32;
    const int lm = lane & 15, q = lane >> 4;
    const int sr = tid >> 2, sc = (tid & 3) * 8;

    for (int k0 = 0; k0 < K; k0 += 32) {
        *(bs8*)&Ah[sr][sc] = *(const bs8*)(Ahg + (size_t)(row0 + sr) * lda + k0 + sc);
        *(bs8*)&Al[sr][sc] = *(const bs8*)(Alg + (size_t)(row0 + sr) * lda + k0 + sc);
        *(bs8*)&Bh[sr][sc] = *(const bs8*)(Bhg + (size_t)(col0 + sr) * ldb + k0 + sc);
        *(bs8*)&Bl[sr][sc] = *(const bs8*)(Blg + (size_t)(col0 + sr) * ldb + k0 + sc);
        __syncthreads();

        bs8 a_h[2], a_l[2], b_h[2], b_l[2];
#pragma unroll
        for (int t = 0; t < 2; t++) {
            a_h[t] = *(bs8*)&Ah[wm0 + t * 16 + lm][q * 8];
            a_l[t] = *(bs8*)&Al[wm0 + t * 16 + lm][q * 8];
            b_h[t] = *(bs8*)&Bh[wn0 + t * 16 + lm][q * 8];
            b_l[t] = *(bs8*)&Bl[wn0 + t * 16 + lm][q * 8];
        }
#pragma unroll
        for (int mt = 0; mt < 2; mt++)
#pragma unroll
            for (int nt = 0; nt < 2; nt++) {
                acc[mt][nt] = __builtin_amdgcn_mfma_f32_16x16x32_bf16(a_h[mt], b_h[nt], acc[mt][nt], 0, 0, 0);
                acc[mt][nt] = __builtin_amdgcn_mfma_f32_16x16x32_bf16(a_h[mt], b_l[nt], acc[mt][nt], 0, 0, 0);
                acc[mt][nt] = __builtin_amdgcn_mfma_f32_16x16x32_bf16(a_l[mt], b_h[nt], acc[mt][nt], 0, 0, 0);
            }
        __syncthreads();
    }
}

// 64x64 fp32 tile -> transposed bf16 hi/lo (dst[n][k] = src[k][n]).
__device__ __forceinline__ void transpose_split_tile(
    const float* __restrict__ src, int src_ld,
    unsigned short* __restrict__ dh, unsigned short* __restrict__ dl, int dst_ld,
    unsigned short (*Th)[72], unsigned short (*Tl)[72])
{
    int tid = threadIdx.x;
    int r = tid >> 2;
    int cb = (tid & 3) * 16;
#pragma unroll
    for (int cc = 0; cc < 16; cc += 4) {
        float4 v = *(const float4*)(src + (size_t)r * src_ld + cb + cc);
        unsigned short hh, ll;
        split2(v.x, hh, ll); Th[cb + cc + 0][r] = hh; Tl[cb + cc + 0][r] = ll;
        split2(v.y, hh, ll); Th[cb + cc + 1][r] = hh; Tl[cb + cc + 1][r] = ll;
        split2(v.z, hh, ll); Th[cb + cc + 2][r] = hh; Tl[cb + cc + 2][r] = ll;
        split2(v.w, hh, ll); Th[cb + cc + 3][r] = hh; Tl[cb + cc + 3][r] = ll;
    }
    __syncthreads();
    int n = tid >> 2, ch = (tid & 3) * 8;
    *(bs8*)(dh + (size_t)n * dst_ld + ch)      = *(bs8*)&Th[n][ch];
    *(bs8*)(dh + (size_t)n * dst_ld + ch + 32) = *(bs8*)&Th[n][ch + 32];
    *(bs8*)(dl + (size_t)n * dst_ld + ch)      = *(bs8*)&Tl[n][ch];
    *(bs8*)(dl + (size_t)n * dst_ld + ch + 32) = *(bs8*)&Tl[n][ch + 32];
}

// flat fp32 -> split bf16 hi/lo, 4096 elems/job, 16/thread.
__device__ __forceinline__ void flat_split_job(
    const float* __restrict__ src, unsigned short* __restrict__ dh,
    unsigned short* __restrict__ dl, size_t base)
{
    unsigned short hh, ll;
#pragma unroll
    for (int g = 0; g < 2; g++) {
        bs8 sh, sl;
#pragma unroll
        for (int cc = 0; cc < 8; cc += 4) {
            float4 v = *(const float4*)(src + base + g * 8 + cc);
            split2(v.x, hh, ll); sh[cc + 0] = (short)hh; sl[cc + 0] = (short)ll;
            split2(v.y, hh, ll); sh[cc + 1] = (short)hh; sl[cc + 1] = (short)ll;
            split2(v.z, hh, ll); sh[cc + 2] = (short)hh; sl[cc + 2] = (short)ll;
            split2(v.w, hh, ll); sh[cc + 3] = (short)hh; sl[cc + 3] = (short)ll;
        }
        *(bs8*)(dh + base + g * 8) = sh;
        *(bs8*)(dl + base + g * 8) = sl;
    }
}

// ---------------------------------------------------------------------------
// Prep, grid 530, one job per block:
//   [0,144)   W0 -> Wt0 transposed split
//   [144,288) W1 -> Wt1 transposed split
//   [288,480) feature -> fh/fl row-major split
//   [480,528) WA via MFMA, operands split on the fly (W read ONCE total):
//             WAt[layer][c][r] = sum_k A1x[k][c] * W[r][k]
//             48 blocks: layer(2) x ctile(2) x rtile(12), 64x64 out each.
//   [528,530) bA[layer][c] = sum_k b[k] * A1x[k][c]
// ---------------------------------------------------------------------------
__global__ __launch_bounds__(256) void prep_k(
    const float* __restrict__ W0, const float* __restrict__ W1,
    const float* __restrict__ A1, const float* __restrict__ feature,
    const float* __restrict__ b0, const float* __restrict__ b1,
    unsigned short* Wt0h, unsigned short* Wt0l,
    unsigned short* Wt1h, unsigned short* Wt1l,
    unsigned short* fh, unsigned short* fl,
    unsigned short* WAth, unsigned short* WAtl,
    float* bA)
{
    __shared__ __align__(16) char smem[20480];
    int id = blockIdx.x, tid = threadIdx.x;
    if (id < 288) {
        unsigned short (*Th)[72] = (unsigned short(*)[72])(smem);
        unsigned short (*Tl)[72] = (unsigned short(*)[72])(smem + 9216);
        if (id < 144) {
            int kt = id / 12, nt = id % 12;
            transpose_split_tile(W0 + (size_t)(kt * 64) * 768 + nt * 64, 768,
                                 Wt0h + (size_t)(nt * 64) * 768 + kt * 64,
                                 Wt0l + (size_t)(nt * 64) * 768 + kt * 64, 768, Th, Tl);
        } else {
            int r = id - 144, kt = r / 12, nt = r % 12;
            transpose_split_tile(W1 + (size_t)(kt * 64) * 768 + nt * 64, 768,
                                 Wt1h + (size_t)(nt * 64) * 768 + kt * 64,
                                 Wt1l + (size_t)(nt * 64) * 768 + kt * 64, 768, Th, Tl);
        }
    } else if (id < 480) {
        flat_split_job(feature, fh, fl, (size_t)(id - 288) * 4096 + tid * 16);
    } else if (id < 528) {
        // --- WA MFMA job, self-splitting operands ---
        int j = id - 480;
        int rt = j % 12, ct = (j / 12) & 1, layer = j / 24;
        const float* W = layer ? W1 : W0;
        const int r0 = rt * 64;
        unsigned short (*Ah)[40] = (unsigned short(*)[40])(smem);
        unsigned short (*Al)[40] = (unsigned short(*)[40])(smem + 5120);
        unsigned short (*Bh)[40] = (unsigned short(*)[40])(smem + 10240);
        unsigned short (*Bl)[40] = (unsigned short(*)[40])(smem + 15360);
        const int lane = tid & 63, wid = tid >> 6;
        const int wm0 = (wid >> 1) * 32, wn0 = (wid & 1) * 32;
        const int lm = lane & 15, q = lane >> 4;
        const int akk = tid & 31, acs = (tid >> 5) * 8;   // A: k-row, c-seg
        const int br = tid >> 2, bks = (tid & 3) * 8;     // B: r-row, k-seg
        f32x4 acc[2][2] = {};
        for (int k0 = 0; k0 < 768; k0 += 32) {
            {   // A-operand: Ah[c][k] = A1[(ct*768 + k0+kk)][c] (transpose-split)
                const float* ap = A1 + (size_t)(ct * 768 + k0 + akk) * 64 + acs;
                float4 v0 = *(const float4*)ap;
                float4 v1 = *(const float4*)(ap + 4);
                unsigned short hv, lv;
                split2(v0.x, hv, lv); Ah[acs + 0][akk] = hv; Al[acs + 0][akk] = lv;
                split2(v0.y, hv, lv); Ah[acs + 1][akk] = hv; Al[acs + 1][akk] = lv;
                split2(v0.z, hv, lv); Ah[acs + 2][akk] = hv; Al[acs + 2][akk] = lv;
                split2(v0.w, hv, lv); Ah[acs + 3][akk] = hv; Al[acs + 3][akk] = lv;
                split2(v1.x, hv, lv); Ah[acs + 4][akk] = hv; Al[acs + 4][akk] = lv;
                split2(v1.y, hv, lv); Ah[acs + 5][akk] = hv; Al[acs + 5][akk] = lv;
                split2(v1.z, hv, lv); Ah[acs + 6][akk] = hv; Al[acs + 6][akk] = lv;
                split2(v1.w, hv, lv); Ah[acs + 7][akk] = hv; Al[acs + 7][akk] = lv;
            }
            {   // B-operand: Bh[r][k] = W[r0+r][k0+k] (row-major split)
                const float* wp = W + (size_t)(r0 + br) * 768 + k0 + bks;
                float4 v0 = *(const float4*)wp;
                float4 v1 = *(const float4*)(wp + 4);
                bs8 sh, sl; unsigned short hv, lv;
                split2(v0.x, hv, lv); sh[0] = (short)hv; sl[0] = (short)lv;
                split2(v0.y, hv, lv); sh[1] = (short)hv; sl[1] = (short)lv;
                split2(v0.z, hv, lv); sh[2] = (short)hv; sl[2] = (short)lv;
                split2(v0.w, hv, lv); sh[3] = (short)hv; sl[3] = (short)lv;
                split2(v1.x, hv, lv); sh[4] = (short)hv; sl[4] = (short)lv;
                split2(v1.y, hv, lv); sh[5] = (short)hv; sl[5] = (short)lv;
                split2(v1.z, hv, lv); sh[6] = (short)hv; sl[6] = (short)lv;
                split2(v1.w, hv, lv); sh[7] = (short)hv; sl[7] = (short)lv;
                *(bs8*)&Bh[br][bks] = sh;
                *(bs8*)&Bl[br][bks] = sl;
            }
            __syncthreads();
            bs8 a_h[2], a_l[2], b_h[2], b_l[2];
#pragma unroll
            for (int t = 0; t < 2; t++) {
                a_h[t] = *(bs8*)&Ah[wm0 + t * 16 + lm][q * 8];
                a_l[t] = *(bs8*)&Al[wm0 + t * 16 + lm][q * 8];
                b_h[t] = *(bs8*)&Bh[wn0 + t * 16 + lm][q * 8];
                b_l[t] = *(bs8*)&Bl[wn0 + t * 16 + lm][q * 8];
            }
#pragma unroll
            for (int mt = 0; mt < 2; mt++)
#pragma unroll
                for (int nt = 0; nt < 2; nt++) {
                    acc[mt][nt] = __builtin_amdgcn_mfma_f32_16x16x32_bf16(a_h[mt], b_h[nt], acc[mt][nt], 0, 0, 0);
                    acc[mt][nt] = __builtin_amdgcn_mfma_f32_16x16x32_bf16(a_h[mt], b_l[nt], acc[mt][nt], 0, 0, 0);
                    acc[mt][nt] = __builtin_amdgcn_mfma_f32_16x16x32_bf16(a_l[mt], b_h[nt], acc[mt][nt], 0, 0, 0);
                }
            __syncthreads();
        }
        // epilogue: D[m=c_local][n=r_local] -> WAt[layer][c0+m][r0+n]
        const int c0 = ct * 64;
        size_t base = (size_t)layer * 98304;
#pragma unroll
        for (int mt = 0; mt < 2; mt++)
#pragma unroll
            for (int nt = 0; nt < 2; nt++) {
                int n = r0 + wn0 + nt * 16 + lm;
#pragma unroll
                for (int i = 0; i < 4; i++) {
                    int m = c0 + wm0 + mt * 16 + q * 4 + i;
                    unsigned short hv, lv;
                    split2(acc[mt][nt][i], hv, lv);
                    WAth[base + (size_t)m * 768 + n] = hv;
                    WAtl[base + (size_t)m * 768 + n] = lv;
                }
            }
    } else {
        float* redb = (float*)(smem);    // 256 f
        int layer = id - 528;
        const float* bv = layer ? b1 : b0;
        int c = tid & 127, half = tid >> 7;
        float acc = 0.f;
        for (int kk = 0; kk < 384; kk++) {
            int k = half * 384 + kk;
            int row = (c < 64 ? k : 768 + k);
            acc += bv[k] * A1[(size_t)row * 64 + (c & 63)];
        }
        redb[tid] = acc;
        __syncthreads();
        if (tid < 128) bA[layer * 128 + tid] = redb[tid] + redb[tid + 128];
    }
}

// ---------------------------------------------------------------------------
// Fused gemm: grid (14, 16). col-tiles 0-11: h = A@W + bias -> transposed
// split hth/htl (attn B). col-tiles 12-13: s = A@WA -> fp32 (bias in score).
// (validated round 7)
// ---------------------------------------------------------------------------
__global__ __launch_bounds__(256) void gemm_fused_k(
    const unsigned short* __restrict__ Ahg, const unsigned short* __restrict__ Alg,
    const unsigned short* __restrict__ Wth, const unsigned short* __restrict__ Wtl,
    const unsigned short* __restrict__ WAth, const unsigned short* __restrict__ WAtl,
    const float* __restrict__ bias,
    unsigned short* __restrict__ hth, unsigned short* __restrict__ htl,
    float* __restrict__ s)
{
    __shared__ unsigned short smem[4][64][40];
    int bx = blockIdx.x, row0 = blockIdx.y * 64;
    const unsigned short* Bh;
    const unsigned short* Bl;
    int col0;
    if (bx < 12) { Bh = Wth;  Bl = Wtl;  col0 = bx * 64; }
    else         { Bh = WAth; Bl = WAtl; col0 = (bx - 12) * 64; }
    f32x4 acc[2][2] = {};
    mfma_loop(Ahg, Alg, 768, Bh, Bl, 768, 768, row0, col0, acc,
              smem[0], smem[1], smem[2], smem[3]);
    int tid = threadIdx.x, lane = tid & 63, wid = tid >> 6;
    int wm0 = (wid >> 1) * 32, wn0 = (wid & 1) * 32;
    int lm = lane & 15, q = lane >> 4;
    if (bx >= 12) {
#pragma unroll
        for (int mt = 0; mt < 2; mt++)
#pragma unroll
            for (int nt = 0; nt < 2; nt++) {
                int c = col0 + wn0 + nt * 16 + lm;
#pragma unroll
                for (int i = 0; i < 4; i++) {
                    int r = row0 + wm0 + mt * 16 + q * 4 + i;
                    s[(size_t)r * 128 + c] = acc[mt][nt][i];
                }
            }
        return;
    }
    __syncthreads();
    unsigned short* flat = &smem[0][0][0];
    unsigned short (*Hi)[69] = (unsigned short(*)[69])flat;
    unsigned short (*Lo)[69] = (unsigned short(*)[69])(flat + 4416);
#pragma unroll
    for (int mt = 0; mt < 2; mt++)
#pragma unroll
        for (int nt = 0; nt < 2; nt++) {
            int c = wn0 + nt * 16 + lm;
            float bv = bias[col0 + c];
#pragma unroll
            for (int i = 0; i < 4; i++) {
                int r = wm0 + mt * 16 + q * 4 + i;
                unsigned short hv, lv;
                split2(acc[mt][nt][i] + bv, hv, lv);
                Hi[r][c] = hv; Lo[r][c] = lv;
            }
        }
    __syncthreads();
    int d = tid >> 2, kq = (tid & 3) * 16;
    int b = row0 >> 7, kb = row0 & 127;
    bs8 th0, th1, tl0, tl1;
#pragma unroll
    for (int e = 0; e < 8; e++) {
        th0[e] = Hi[kq + e][d];     th1[e] = Hi[kq + 8 + e][d];
        tl0[e] = Lo[kq + e][d];     tl1[e] = Lo[kq + 8 + e][d];
    }
    size_t to = ((size_t)b * 768 + col0 + d) * 128 + kb + kq;
    *(bs8*)(hth + to) = th0; *(bs8*)(hth + to + 8) = th1;
    *(bs8*)(htl + to) = tl0; *(bs8*)(htl + to + 8) = tl1;
}

// ---------------------------------------------------------------------------
// score_k: masked score + exp (no max-shift; |e|<<80 by construction, masked
// entries = 0 exactly). Writes split exp to ph/pl + per-block sum psum[b][32].
// grid (32 i-tiles, 8 b), block 256. (validated round 7)
// ---------------------------------------------------------------------------
__global__ __launch_bounds__(256) void score_k(
    const float* __restrict__ s, const int* __restrict__ adj,
    const float* __restrict__ ab1, const float* __restrict__ A2,
    const float* __restrict__ ab2, const float* __restrict__ bA,
    unsigned short* __restrict__ ph, unsigned short* __restrict__ pl,
    float* __restrict__ psum)
{
    __shared__ float st[128][65];
    __shared__ float ss[4][65];
    __shared__ float a2s[64];
    __shared__ float warr[4];
    const int bx = blockIdx.x, b = blockIdx.y, tid = threadIdx.x;
    const int i0 = bx * 4;
    for (int idx = tid; idx < 8192; idx += 256) {
        int j = idx >> 6, h2 = idx & 63;
        st[j][h2] = s[(size_t)(b * 128 + j) * 128 + 64 + h2] + bA[64 + h2];
    }
    {
        int i = tid >> 6, h2 = tid & 63;
        ss[i][h2] = s[(size_t)(b * 128 + i0 + i) * 128 + h2] + bA[h2] + ab1[h2];
    }
    if (tid < 64) a2s[tid] = A2[tid];
    __syncthreads();
    const float ab2v = ab2[0];
    const int rr = tid >> 7;
    const int j = tid & 127;
    const int r0 = rr * 2, r1 = rr * 2 + 1;
    float acc0 = 0.f, acc1 = 0.f;
#pragma unroll 4
    for (int h2 = 0; h2 < 64; h2++) {
        float bb = st[j][h2];
        float cv = a2s[h2];
        acc0 = fmaf(fmaxf(ss[r0][h2] + bb, 0.f), cv, acc0);
        acc1 = fmaf(fmaxf(ss[r1][h2] + bb, 0.f), cv, acc1);
    }
    float e0 = acc0 + ab2v; e0 = (e0 > 0.f) ? e0 : SLOPE_V * e0;
    float e1 = acc1 + ab2v; e1 = (e1 > 0.f) ? e1 : SLOPE_V * e1;
    size_t o0 = (size_t)b * 16384 + (size_t)(i0 + r0) * 128 + j;
    size_t o1 = (size_t)b * 16384 + (size_t)(i0 + r1) * 128 + j;
    float v0 = adj[o0] ? expf(e0) : 0.f;
    float v1 = adj[o1] ? expf(e1) : 0.f;
    unsigned short hv, lv;
    split2(v0, hv, lv); ph[o0] = hv; pl[o0] = lv;
    split2(v1, hv, lv); ph[o1] = hv; pl[o1] = lv;
    float vs = v0 + v1;
#pragma unroll
    for (int o = 32; o > 0; o >>= 1) vs += __shfl_down(vs, o);
    if ((tid & 63) == 0) warr[tid >> 6] = vs;
    __syncthreads();
    if (tid == 0) psum[b * 32 + bx] = warr[0] + warr[1] + warr[2] + warr[3];
}

// ---------------------------------------------------------------------------
// attn: node[b] = (1/sum_b) * P[b] @ h[b]; alpha from psum partials.
// Outputs fp32 node AND split ndh/ndl. grid (12,2,8). (validated round 7)
// ---------------------------------------------------------------------------
__global__ __launch_bounds__(256) void attn_mfma_k(
    const unsigned short* __restrict__ ph, const unsigned short* __restrict__ pl,
    const unsigned short* __restrict__ hth, const unsigned short* __restrict__ htl,
    const float* __restrict__ psum, float* __restrict__ node,
    unsigned short* __restrict__ nodeh, unsigned short* __restrict__ nodel)
{
    __shared__ unsigned short smem[4][64][40];
    __shared__ float sred[33];
    int b = blockIdx.z;
    int row0 = blockIdx.y * 64, col0 = blockIdx.x * 64;
    int tid = threadIdx.x;
    if (tid < 32) sred[tid] = psum[b * 32 + tid];
    __syncthreads();
    if (tid == 0) {
        float t = 0.f;
#pragma unroll
        for (int i = 0; i < 32; i++) t += sred[i];
        sred[32] = 1.0f / t;
    }
    __syncthreads();
    float alpha = sred[32];
    f32x4 acc[2][2] = {};
    mfma_loop(ph + (size_t)b * 16384, pl + (size_t)b * 16384, 128,
              hth + (size_t)b * 98304, htl + (size_t)b * 98304, 128, 128,
              row0, col0, acc, smem[0], smem[1], smem[2], smem[3]);
    __syncthreads();
    float* C = node + (size_t)b * 98304;
    unsigned short* flat = &smem[0][0][0];
    unsigned short (*Hi)[69] = (unsigned short(*)[69])flat;
    unsigned short (*Lo)[69] = (unsigned short(*)[69])(flat + 4416);
    int lane = tid & 63, wid = tid >> 6;
    int wm0 = (wid >> 1) * 32, wn0 = (wid & 1) * 32;
    int lm = lane & 15, q = lane >> 4;
#pragma unroll
    for (int mt = 0; mt < 2; mt++)
#pragma unroll
        for (int nt = 0; nt < 2; nt++) {
            int c = wn0 + nt * 16 + lm;
#pragma unroll
            for (int i = 0; i < 4; i++) {
                int r = wm0 + mt * 16 + q * 4 + i;
                float v = acc[mt][nt][i] * alpha;
                C[(size_t)(row0 + r) * 768 + col0 + c] = v;
                unsigned short hv, lv;
                split2(v, hv, lv);
                Hi[r][c] = hv; Lo[r][c] = lv;
            }
        }
    __syncthreads();
    int r = tid >> 2, cq = (tid & 3) * 16;
    bs8 vh0, vh1, vl0, vl1;
#pragma unroll
    for (int e = 0; e < 8; e++) {
        vh0[e] = Hi[r][cq + e];     vh1[e] = Hi[r][cq + 8 + e];
        vl0[e] = Lo[r][cq + e];     vl1[e] = Lo[r][cq + 8 + e];
    }
    size_t ro = (size_t)(b * 128 + row0 + r) * 768 + col0 + cq;
    *(bs8*)(nodeh + ro) = vh0; *(bs8*)(nodeh + ro + 8) = vh1;
    *(bs8*)(nodel + ro) = vl0; *(bs8*)(nodel + ro + 8) = vl1;
}

// ---------------------------------------------------------------------------
// Fused graph-sum + batch-norm. grid 12, block 512. (validated round 4)
// ---------------------------------------------------------------------------
__global__ __launch_bounds__(512) void gsum_bnorm_k(
    const float* __restrict__ node, const float* __restrict__ gamma,
    const float* __restrict__ beta, float* __restrict__ out)
{
    __shared__ float gbuf[8][64];
    __shared__ float mean_s[64], inv_s[64];
    int tid = threadIdx.x;
    int bg = tid >> 6, dl = tid & 63;
    int d = blockIdx.x * 64 + dl;
    float v = 0.f;
    for (int i = 0; i < 128; i++)
        v += node[(size_t)(bg * 128 + i) * 768 + d];
    gbuf[bg][dl] = v;
    __syncthreads();
    if (tid < 64) {
        float m = 0.f;
#pragma unroll
        for (int b = 0; b < 8; b++) m += gbuf[b][tid];
        m *= 0.125f;
        float var = 0.f;
#pragma unroll
        for (int b = 0; b < 8; b++) { float t = gbuf[b][tid] - m; var += t * t; }
        var *= 0.125f;
        mean_s[tid] = m;
        inv_s[tid] = 1.0f / sqrtf(var + EPS_V);
    }
    __syncthreads();
    out[bg * 768 + d] = gamma[d] * (v - mean_s[dl]) * inv_s[dl] + beta[d];
}

// ---------------------------------------------------------------------------
extern "C" void kernel_launch(void* const* d_in, const int* in_sizes, int n_in,
                              void* d_out, int out_size, void* d_ws, size_t ws_size,
                              hipStream_t stream)
{
    const float* feature = (const float*)d_in[0];
    // d_in[1] = aspect: unused by the reference
    const int*   adj     = (const int*)d_in[2];
    const float* W0      = (const float*)d_in[3];
    const float* b0      = (const float*)d_in[4];
    const float* W1      = (const float*)d_in[5];
    const float* b1      = (const float*)d_in[6];
    const float* A1      = (const float*)d_in[7];
    const float* ab1     = (const float*)d_in[8];
    const float* A2      = (const float*)d_in[9];
    const float* ab2     = (const float*)d_in[10];
    const float* gamma   = (const float*)d_in[11];
    const float* beta    = (const float*)d_in[12];

    float* ws    = (float*)d_ws;
    float* s     = ws;               // 131072
    float* psum  = ws + 131072;      // 256
    float* bA    = ws + 131328;      // 256
    unsigned short* u = (unsigned short*)(ws + 131584);  // 16B-aligned
    unsigned short* Wt0h = u;                    // 589824 each
    unsigned short* Wt0l = Wt0h + 589824;
    unsigned short* Wt1h = Wt0l + 589824;
    unsigned short* Wt1l = Wt1h + 589824;
    unsigned short* WAth = Wt1l + 589824;        // 196608 each (2 layers)
    unsigned short* WAtl = WAth + 196608;
    unsigned short* fh   = WAtl + 196608;        // 786432 each from here
    unsigned short* fl   = fh + 786432;
    unsigned short* hth  = fl + 786432;
    unsigned short* htl  = hth + 786432;
    unsigned short* ndh  = htl + 786432;
    unsigned short* ndl  = ndh + 786432;
    unsigned short* ph   = ndl + 786432;         // 131072 each
    unsigned short* pl   = ph + 131072;

    float* out       = (float*)d_out;
    float* graph_out = out;          // (8,768)
    float* node_out  = out + 6144;   // (8,128,768)

    prep_k<<<530, 256, 0, stream>>>(W0, W1, A1, feature, b0, b1,
                                    Wt0h, Wt0l, Wt1h, Wt1l,
                                    fh, fl, WAth, WAtl, bA);

    for (int layer = 0; layer < 2; layer++) {
        const unsigned short* Wth = layer ? Wt1h : Wt0h;
        const unsigned short* Wtl = layer ? Wt1l : Wt0l;
        const float* bb = layer ? b1 : b0;
        const unsigned short* Ahg = layer ? ndh : fh;
        const unsigned short* Alg = layer ? ndl : fl;
        gemm_fused_k<<<dim3(14, 16), 256, 0, stream>>>(
            Ahg, Alg, Wth, Wtl, WAth + (size_t)layer * 98304,
            WAtl + (size_t)layer * 98304, bb, hth, htl, s);
        score_k<<<dim3(32, 8), 256, 0, stream>>>(s, adj, ab1, A2, ab2,
                                                 bA + layer * 128, ph, pl, psum);
        attn_mfma_k<<<dim3(12, 2, 8), 256, 0, stream>>>(ph, pl, hth, htl, psum,
                                                        node_out, ndh, ndl);
    }
    gsum_bnorm_k<<<12, 512, 0, stream>>>(node_out, gamma, beta, graph_out);
}

// Round 11
// 176.663 us; speedup vs baseline: 4.1311x; 1.0281x over previous
//
#include <hip/hip_runtime.h>
#include <math.h>

#define NEG_V (-1e30f)
#define SLOPE_V 0.01f
#define EPS_V 1e-5f

typedef __attribute__((ext_vector_type(8))) short bs8;    // 8 bf16 (4 VGPRs)
typedef __attribute__((ext_vector_type(4))) float f32x4;  // mfma acc

// Split fp32 x into bf16 hi + bf16 lo (RNE both). x ≈ hi + lo, rel err ~2^-17.
__device__ __forceinline__ void split2(float x, unsigned short& hi, unsigned short& lo) {
    unsigned u = __float_as_uint(x);
    unsigned h = (u + 0x7FFFu + ((u >> 16) & 1u)) >> 16;
    hi = (unsigned short)h;
    float hf = __uint_as_float(h << 16);
    float l = x - hf;
    unsigned ul = __float_as_uint(l);
    lo = (unsigned short)((ul + 0x7FFFu + ((ul >> 16) & 1u)) >> 16);
}

// ---------------------------------------------------------------------------
// Software-pipelined split-bf16 MFMA mainloop (math identical to the
// validated rounds-4/6/7 loop; scheduling changed only):
//  - double-buffered LDS stages (buf[2][4][64][40], 40 KB): ONE barrier/iter
//  - register prefetch: iter k+1's global b128 loads issued right after the
//    barrier, consumed at the next LDS write -> ~200cyc L2 latency overlaps
//    the frag-read + 12-MFMA phase (needed: ~1 blk/CU => no TLP to hide it).
// Caller must __syncthreads() before reusing the LDS for an epilogue.
// ---------------------------------------------------------------------------
__device__ __forceinline__ void mfma_loop(
    const unsigned short* __restrict__ Ahg, const unsigned short* __restrict__ Alg,
    int lda,
    const unsigned short* __restrict__ Bhg, const unsigned short* __restrict__ Blg,
    int ldb, int K, int row0, int col0,
    f32x4 (&acc)[2][2],
    unsigned short (*buf)[64][40])   // buf[8]: stage*4 + {Ah,Al,Bh,Bl}
{
    const int tid = threadIdx.x;
    const int lane = tid & 63, wid = tid >> 6;
    const int wm0 = (wid >> 1) * 32, wn0 = (wid & 1) * 32;
    const int lm = lane & 15, q = lane >> 4;
    const int sr = tid >> 2, sc = (tid & 3) * 8;

    const unsigned short* pAh = Ahg + (size_t)(row0 + sr) * lda + sc;
    const unsigned short* pAl = Alg + (size_t)(row0 + sr) * lda + sc;
    const unsigned short* pBh = Bhg + (size_t)(col0 + sr) * ldb + sc;
    const unsigned short* pBl = Blg + (size_t)(col0 + sr) * ldb + sc;

    bs8 rAh = *(const bs8*)(pAh);
    bs8 rAl = *(const bs8*)(pAl);
    bs8 rBh = *(const bs8*)(pBh);
    bs8 rBl = *(const bs8*)(pBl);

    int st = 0;
    for (int k0 = 0; k0 < K; k0 += 32) {
        unsigned short (*Ah)[40] = buf[st * 4 + 0];
        unsigned short (*Al)[40] = buf[st * 4 + 1];
        unsigned short (*Bh)[40] = buf[st * 4 + 2];
        unsigned short (*Bl)[40] = buf[st * 4 + 3];
        *(bs8*)&Ah[sr][sc] = rAh;
        *(bs8*)&Al[sr][sc] = rAl;
        *(bs8*)&Bh[sr][sc] = rBh;
        *(bs8*)&Bl[sr][sc] = rBl;
        __syncthreads();
        if (k0 + 32 < K) {
            rAh = *(const bs8*)(pAh + k0 + 32);
            rAl = *(const bs8*)(pAl + k0 + 32);
            rBh = *(const bs8*)(pBh + k0 + 32);
            rBl = *(const bs8*)(pBl + k0 + 32);
        }
        bs8 a_h[2], a_l[2], b_h[2], b_l[2];
#pragma unroll
        for (int t = 0; t < 2; t++) {
            a_h[t] = *(bs8*)&Ah[wm0 + t * 16 + lm][q * 8];
            a_l[t] = *(bs8*)&Al[wm0 + t * 16 + lm][q * 8];
            b_h[t] = *(bs8*)&Bh[wn0 + t * 16 + lm][q * 8];
            b_l[t] = *(bs8*)&Bl[wn0 + t * 16 + lm][q * 8];
        }
#pragma unroll
        for (int mt = 0; mt < 2; mt++)
#pragma unroll
            for (int nt = 0; nt < 2; nt++) {
                acc[mt][nt] = __builtin_amdgcn_mfma_f32_16x16x32_bf16(a_h[mt], b_h[nt], acc[mt][nt], 0, 0, 0);
                acc[mt][nt] = __builtin_amdgcn_mfma_f32_16x16x32_bf16(a_h[mt], b_l[nt], acc[mt][nt], 0, 0, 0);
                acc[mt][nt] = __builtin_amdgcn_mfma_f32_16x16x32_bf16(a_l[mt], b_h[nt], acc[mt][nt], 0, 0, 0);
            }
        st ^= 1;
        // no second barrier: next iteration writes the OTHER stage; the
        // barrier above plus per-wave program order make W_{i+2} vs R_i safe.
    }
}

// 64x64 fp32 tile -> transposed bf16 hi/lo (dst[n][k] = src[k][n]).
__device__ __forceinline__ void transpose_split_tile(
    const float* __restrict__ src, int src_ld,
    unsigned short* __restrict__ dh, unsigned short* __restrict__ dl, int dst_ld,
    unsigned short (*Th)[72], unsigned short (*Tl)[72])
{
    int tid = threadIdx.x;
    int r = tid >> 2;
    int cb = (tid & 3) * 16;
#pragma unroll
    for (int cc = 0; cc < 16; cc += 4) {
        float4 v = *(const float4*)(src + (size_t)r * src_ld + cb + cc);
        unsigned short hh, ll;
        split2(v.x, hh, ll); Th[cb + cc + 0][r] = hh; Tl[cb + cc + 0][r] = ll;
        split2(v.y, hh, ll); Th[cb + cc + 1][r] = hh; Tl[cb + cc + 1][r] = ll;
        split2(v.z, hh, ll); Th[cb + cc + 2][r] = hh; Tl[cb + cc + 2][r] = ll;
        split2(v.w, hh, ll); Th[cb + cc + 3][r] = hh; Tl[cb + cc + 3][r] = ll;
    }
    __syncthreads();
    int n = tid >> 2, ch = (tid & 3) * 8;
    *(bs8*)(dh + (size_t)n * dst_ld + ch)      = *(bs8*)&Th[n][ch];
    *(bs8*)(dh + (size_t)n * dst_ld + ch + 32) = *(bs8*)&Th[n][ch + 32];
    *(bs8*)(dl + (size_t)n * dst_ld + ch)      = *(bs8*)&Tl[n][ch];
    *(bs8*)(dl + (size_t)n * dst_ld + ch + 32) = *(bs8*)&Tl[n][ch + 32];
}

// flat fp32 -> split bf16 hi/lo, 4096 elems/job, 16/thread.
__device__ __forceinline__ void flat_split_job(
    const float* __restrict__ src, unsigned short* __restrict__ dh,
    unsigned short* __restrict__ dl, size_t base)
{
    unsigned short hh, ll;
#pragma unroll
    for (int g = 0; g < 2; g++) {
        bs8 sh, sl;
#pragma unroll
        for (int cc = 0; cc < 8; cc += 4) {
            float4 v = *(const float4*)(src + base + g * 8 + cc);
            split2(v.x, hh, ll); sh[cc + 0] = (short)hh; sl[cc + 0] = (short)ll;
            split2(v.y, hh, ll); sh[cc + 1] = (short)hh; sl[cc + 1] = (short)ll;
            split2(v.z, hh, ll); sh[cc + 2] = (short)hh; sl[cc + 2] = (short)ll;
            split2(v.w, hh, ll); sh[cc + 3] = (short)hh; sl[cc + 3] = (short)ll;
        }
        *(bs8*)(dh + base + g * 8) = sh;
        *(bs8*)(dl + base + g * 8) = sl;
    }
}

// ---------------------------------------------------------------------------
// Prep, grid 530 (validated round 10):
//   [0,144)   W0 -> Wt0 transposed split
//   [144,288) W1 -> Wt1 transposed split
//   [288,480) feature -> fh/fl row-major split
//   [480,528) WA via MFMA, operands split on the fly (W read once total)
//   [528,530) bA[layer][c] = sum_k b[k] * A1x[k][c]
// ---------------------------------------------------------------------------
__global__ __launch_bounds__(256) void prep_k(
    const float* __restrict__ W0, const float* __restrict__ W1,
    const float* __restrict__ A1, const float* __restrict__ feature,
    const float* __restrict__ b0, const float* __restrict__ b1,
    unsigned short* Wt0h, unsigned short* Wt0l,
    unsigned short* Wt1h, unsigned short* Wt1l,
    unsigned short* fh, unsigned short* fl,
    unsigned short* WAth, unsigned short* WAtl,
    float* bA)
{
    __shared__ __align__(16) char smem[20480];
    int id = blockIdx.x, tid = threadIdx.x;
    if (id < 288) {
        unsigned short (*Th)[72] = (unsigned short(*)[72])(smem);
        unsigned short (*Tl)[72] = (unsigned short(*)[72])(smem + 9216);
        if (id < 144) {
            int kt = id / 12, nt = id % 12;
            transpose_split_tile(W0 + (size_t)(kt * 64) * 768 + nt * 64, 768,
                                 Wt0h + (size_t)(nt * 64) * 768 + kt * 64,
                                 Wt0l + (size_t)(nt * 64) * 768 + kt * 64, 768, Th, Tl);
        } else {
            int r = id - 144, kt = r / 12, nt = r % 12;
            transpose_split_tile(W1 + (size_t)(kt * 64) * 768 + nt * 64, 768,
                                 Wt1h + (size_t)(nt * 64) * 768 + kt * 64,
                                 Wt1l + (size_t)(nt * 64) * 768 + kt * 64, 768, Th, Tl);
        }
    } else if (id < 480) {
        flat_split_job(feature, fh, fl, (size_t)(id - 288) * 4096 + tid * 16);
    } else if (id < 528) {
        // --- WA MFMA job, self-splitting operands ---
        int j = id - 480;
        int rt = j % 12, ct = (j / 12) & 1, layer = j / 24;
        const float* W = layer ? W1 : W0;
        const int r0 = rt * 64;
        unsigned short (*Ah)[40] = (unsigned short(*)[40])(smem);
        unsigned short (*Al)[40] = (unsigned short(*)[40])(smem + 5120);
        unsigned short (*Bh)[40] = (unsigned short(*)[40])(smem + 10240);
        unsigned short (*Bl)[40] = (unsigned short(*)[40])(smem + 15360);
        const int lane = tid & 63, wid = tid >> 6;
        const int wm0 = (wid >> 1) * 32, wn0 = (wid & 1) * 32;
        const int lm = lane & 15, q = lane >> 4;
        const int akk = tid & 31, acs = (tid >> 5) * 8;   // A: k-row, c-seg
        const int br = tid >> 2, bks = (tid & 3) * 8;     // B: r-row, k-seg
        f32x4 acc[2][2] = {};
        for (int k0 = 0; k0 < 768; k0 += 32) {
            {   // A-operand: Ah[c][k] = A1[(ct*768 + k0+kk)][c] (transpose-split)
                const float* ap = A1 + (size_t)(ct * 768 + k0 + akk) * 64 + acs;
                float4 v0 = *(const float4*)ap;
                float4 v1 = *(const float4*)(ap + 4);
                unsigned short hv, lv;
                split2(v0.x, hv, lv); Ah[acs + 0][akk] = hv; Al[acs + 0][akk] = lv;
                split2(v0.y, hv, lv); Ah[acs + 1][akk] = hv; Al[acs + 1][akk] = lv;
                split2(v0.z, hv, lv); Ah[acs + 2][akk] = hv; Al[acs + 2][akk] = lv;
                split2(v0.w, hv, lv); Ah[acs + 3][akk] = hv; Al[acs + 3][akk] = lv;
                split2(v1.x, hv, lv); Ah[acs + 4][akk] = hv; Al[acs + 4][akk] = lv;
                split2(v1.y, hv, lv); Ah[acs + 5][akk] = hv; Al[acs + 5][akk] = lv;
                split2(v1.z, hv, lv); Ah[acs + 6][akk] = hv; Al[acs + 6][akk] = lv;
                split2(v1.w, hv, lv); Ah[acs + 7][akk] = hv; Al[acs + 7][akk] = lv;
            }
            {   // B-operand: Bh[r][k] = W[r0+r][k0+k] (row-major split)
                const float* wp = W + (size_t)(r0 + br) * 768 + k0 + bks;
                float4 v0 = *(const float4*)wp;
                float4 v1 = *(const float4*)(wp + 4);
                bs8 sh, sl; unsigned short hv, lv;
                split2(v0.x, hv, lv); sh[0] = (short)hv; sl[0] = (short)lv;
                split2(v0.y, hv, lv); sh[1] = (short)hv; sl[1] = (short)lv;
                split2(v0.z, hv, lv); sh[2] = (short)hv; sl[2] = (short)lv;
                split2(v0.w, hv, lv); sh[3] = (short)hv; sl[3] = (short)lv;
                split2(v1.x, hv, lv); sh[4] = (short)hv; sl[4] = (short)lv;
                split2(v1.y, hv, lv); sh[5] = (short)hv; sl[5] = (short)lv;
                split2(v1.z, hv, lv); sh[6] = (short)hv; sl[6] = (short)lv;
                split2(v1.w, hv, lv); sh[7] = (short)hv; sl[7] = (short)lv;
                *(bs8*)&Bh[br][bks] = sh;
                *(bs8*)&Bl[br][bks] = sl;
            }
            __syncthreads();
            bs8 a_h[2], a_l[2], b_h[2], b_l[2];
#pragma unroll
            for (int t = 0; t < 2; t++) {
                a_h[t] = *(bs8*)&Ah[wm0 + t * 16 + lm][q * 8];
                a_l[t] = *(bs8*)&Al[wm0 + t * 16 + lm][q * 8];
                b_h[t] = *(bs8*)&Bh[wn0 + t * 16 + lm][q * 8];
                b_l[t] = *(bs8*)&Bl[wn0 + t * 16 + lm][q * 8];
            }
#pragma unroll
            for (int mt = 0; mt < 2; mt++)
#pragma unroll
                for (int nt = 0; nt < 2; nt++) {
                    acc[mt][nt] = __builtin_amdgcn_mfma_f32_16x16x32_bf16(a_h[mt], b_h[nt], acc[mt][nt], 0, 0, 0);
                    acc[mt][nt] = __builtin_amdgcn_mfma_f32_16x16x32_bf16(a_h[mt], b_l[nt], acc[mt][nt], 0, 0, 0);
                    acc[mt][nt] = __builtin_amdgcn_mfma_f32_16x16x32_bf16(a_l[mt], b_h[nt], acc[mt][nt], 0, 0, 0);
                }
            __syncthreads();
        }
        // epilogue: D[m=c_local][n=r_local] -> WAt[layer][c0+m][r0+n]
        const int c0 = ct * 64;
        size_t base = (size_t)layer * 98304;
#pragma unroll
        for (int mt = 0; mt < 2; mt++)
#pragma unroll
            for (int nt = 0; nt < 2; nt++) {
                int n = r0 + wn0 + nt * 16 + lm;
#pragma unroll
                for (int i = 0; i < 4; i++) {
                    int m = c0 + wm0 + mt * 16 + q * 4 + i;
                    unsigned short hv, lv;
                    split2(acc[mt][nt][i], hv, lv);
                    WAth[base + (size_t)m * 768 + n] = hv;
                    WAtl[base + (size_t)m * 768 + n] = lv;
                }
            }
    } else {
        float* redb = (float*)(smem);    // 256 f
        int layer = id - 528;
        const float* bv = layer ? b1 : b0;
        int c = tid & 127, half = tid >> 7;
        float acc = 0.f;
        for (int kk = 0; kk < 384; kk++) {
            int k = half * 384 + kk;
            int row = (c < 64 ? k : 768 + k);
            acc += bv[k] * A1[(size_t)row * 64 + (c & 63)];
        }
        redb[tid] = acc;
        __syncthreads();
        if (tid < 128) bA[layer * 128 + tid] = redb[tid] + redb[tid + 128];
    }
}

// ---------------------------------------------------------------------------
// Fused gemm: grid (14, 16). col-tiles 0-11: h = A@W + bias -> transposed
// split hth/htl (attn B). col-tiles 12-13: s = A@WA -> fp32 (bias in score).
// Pipelined mainloop (this round). Epilogues unchanged (validated round 7).
// ---------------------------------------------------------------------------
__global__ __launch_bounds__(256) void gemm_fused_k(
    const unsigned short* __restrict__ Ahg, const unsigned short* __restrict__ Alg,
    const unsigned short* __restrict__ Wth, const unsigned short* __restrict__ Wtl,
    const unsigned short* __restrict__ WAth, const unsigned short* __restrict__ WAtl,
    const float* __restrict__ bias,
    unsigned short* __restrict__ hth, unsigned short* __restrict__ htl,
    float* __restrict__ s)
{
    __shared__ unsigned short smem[8][64][40];   // 40 KB: 2-stage x 4 bufs
    int bx = blockIdx.x, row0 = blockIdx.y * 64;
    const unsigned short* Bh;
    const unsigned short* Bl;
    int col0;
    if (bx < 12) { Bh = Wth;  Bl = Wtl;  col0 = bx * 64; }
    else         { Bh = WAth; Bl = WAtl; col0 = (bx - 12) * 64; }
    f32x4 acc[2][2] = {};
    mfma_loop(Ahg, Alg, 768, Bh, Bl, 768, 768, row0, col0, acc, smem);
    int tid = threadIdx.x, lane = tid & 63, wid = tid >> 6;
    int wm0 = (wid >> 1) * 32, wn0 = (wid & 1) * 32;
    int lm = lane & 15, q = lane >> 4;
    if (bx >= 12) {
#pragma unroll
        for (int mt = 0; mt < 2; mt++)
#pragma unroll
            for (int nt = 0; nt < 2; nt++) {
                int c = col0 + wn0 + nt * 16 + lm;
#pragma unroll
                for (int i = 0; i < 4; i++) {
                    int r = row0 + wm0 + mt * 16 + q * 4 + i;
                    s[(size_t)r * 128 + c] = acc[mt][nt][i];
                }
            }
        return;
    }
    __syncthreads();   // drain last-stage LDS reads before epilogue reuse
    unsigned short* flat = &smem[0][0][0];
    unsigned short (*Hi)[69] = (unsigned short(*)[69])flat;
    unsigned short (*Lo)[69] = (unsigned short(*)[69])(flat + 4416);
#pragma unroll
    for (int mt = 0; mt < 2; mt++)
#pragma unroll
        for (int nt = 0; nt < 2; nt++) {
            int c = wn0 + nt * 16 + lm;
            float bv = bias[col0 + c];
#pragma unroll
            for (int i = 0; i < 4; i++) {
                int r = wm0 + mt * 16 + q * 4 + i;
                unsigned short hv, lv;
                split2(acc[mt][nt][i] + bv, hv, lv);
                Hi[r][c] = hv; Lo[r][c] = lv;
            }
        }
    __syncthreads();
    int d = tid >> 2, kq = (tid & 3) * 16;
    int b = row0 >> 7, kb = row0 & 127;
    bs8 th0, th1, tl0, tl1;
#pragma unroll
    for (int e = 0; e < 8; e++) {
        th0[e] = Hi[kq + e][d];     th1[e] = Hi[kq + 8 + e][d];
        tl0[e] = Lo[kq + e][d];     tl1[e] = Lo[kq + 8 + e][d];
    }
    size_t to = ((size_t)b * 768 + col0 + d) * 128 + kb + kq;
    *(bs8*)(hth + to) = th0; *(bs8*)(hth + to + 8) = th1;
    *(bs8*)(htl + to) = tl0; *(bs8*)(htl + to + 8) = tl1;
}

// ---------------------------------------------------------------------------
// score_k: masked score + exp (no max-shift; |e|<<80 by construction, masked
// entries = 0 exactly). Writes split exp to ph/pl + per-block sum psum[b][32].
// grid (32 i-tiles, 8 b), block 256. (validated round 7)
// ---------------------------------------------------------------------------
__global__ __launch_bounds__(256) void score_k(
    const float* __restrict__ s, const int* __restrict__ adj,
    const float* __restrict__ ab1, const float* __restrict__ A2,
    const float* __restrict__ ab2, const float* __restrict__ bA,
    unsigned short* __restrict__ ph, unsigned short* __restrict__ pl,
    float* __restrict__ psum)
{
    __shared__ float st[128][65];
    __shared__ float ss[4][65];
    __shared__ float a2s[64];
    __shared__ float warr[4];
    const int bx = blockIdx.x, b = blockIdx.y, tid = threadIdx.x;
    const int i0 = bx * 4;
    for (int idx = tid; idx < 8192; idx += 256) {
        int j = idx >> 6, h2 = idx & 63;
        st[j][h2] = s[(size_t)(b * 128 + j) * 128 + 64 + h2] + bA[64 + h2];
    }
    {
        int i = tid >> 6, h2 = tid & 63;
        ss[i][h2] = s[(size_t)(b * 128 + i0 + i) * 128 + h2] + bA[h2] + ab1[h2];
    }
    if (tid < 64) a2s[tid] = A2[tid];
    __syncthreads();
    const float ab2v = ab2[0];
    const int rr = tid >> 7;
    const int j = tid & 127;
    const int r0 = rr * 2, r1 = rr * 2 + 1;
    float acc0 = 0.f, acc1 = 0.f;
#pragma unroll 4
    for (int h2 = 0; h2 < 64; h2++) {
        float bb = st[j][h2];
        float cv = a2s[h2];
        acc0 = fmaf(fmaxf(ss[r0][h2] + bb, 0.f), cv, acc0);
        acc1 = fmaf(fmaxf(ss[r1][h2] + bb, 0.f), cv, acc1);
    }
    float e0 = acc0 + ab2v; e0 = (e0 > 0.f) ? e0 : SLOPE_V * e0;
    float e1 = acc1 + ab2v; e1 = (e1 > 0.f) ? e1 : SLOPE_V * e1;
    size_t o0 = (size_t)b * 16384 + (size_t)(i0 + r0) * 128 + j;
    size_t o1 = (size_t)b * 16384 + (size_t)(i0 + r1) * 128 + j;
    float v0 = adj[o0] ? expf(e0) : 0.f;
    float v1 = adj[o1] ? expf(e1) : 0.f;
    unsigned short hv, lv;
    split2(v0, hv, lv); ph[o0] = hv; pl[o0] = lv;
    split2(v1, hv, lv); ph[o1] = hv; pl[o1] = lv;
    float vs = v0 + v1;
#pragma unroll
    for (int o = 32; o > 0; o >>= 1) vs += __shfl_down(vs, o);
    if ((tid & 63) == 0) warr[tid >> 6] = vs;
    __syncthreads();
    if (tid == 0) psum[b * 32 + bx] = warr[0] + warr[1] + warr[2] + warr[3];
}

// ---------------------------------------------------------------------------
// attn: node[b] = (1/sum_b) * P[b] @ h[b]; alpha from psum partials.
// Pipelined mainloop. Outputs fp32 node AND split ndh/ndl. grid (12,2,8).
// ---------------------------------------------------------------------------
__global__ __launch_bounds__(256) void attn_mfma_k(
    const unsigned short* __restrict__ ph, const unsigned short* __restrict__ pl,
    const unsigned short* __restrict__ hth, const unsigned short* __restrict__ htl,
    const float* __restrict__ psum, float* __restrict__ node,
    unsigned short* __restrict__ nodeh, unsigned short* __restrict__ nodel)
{
    __shared__ unsigned short smem[8][64][40];   // 40 KB
    __shared__ float sred[33];
    int b = blockIdx.z;
    int row0 = blockIdx.y * 64, col0 = blockIdx.x * 64;
    int tid = threadIdx.x;
    if (tid < 32) sred[tid] = psum[b * 32 + tid];
    __syncthreads();
    if (tid == 0) {
        float t = 0.f;
#pragma unroll
        for (int i = 0; i < 32; i++) t += sred[i];
        sred[32] = 1.0f / t;
    }
    __syncthreads();
    float alpha = sred[32];
    f32x4 acc[2][2] = {};
    mfma_loop(ph + (size_t)b * 16384, pl + (size_t)b * 16384, 128,
              hth + (size_t)b * 98304, htl + (size_t)b * 98304, 128, 128,
              row0, col0, acc, smem);
    __syncthreads();   // drain last-stage LDS reads before epilogue reuse
    float* C = node + (size_t)b * 98304;
    unsigned short* flat = &smem[0][0][0];
    unsigned short (*Hi)[69] = (unsigned short(*)[69])flat;
    unsigned short (*Lo)[69] = (unsigned short(*)[69])(flat + 4416);
    int lane = tid & 63, wid = tid >> 6;
    int wm0 = (wid >> 1) * 32, wn0 = (wid & 1) * 32;
    int lm = lane & 15, q = lane >> 4;
#pragma unroll
    for (int mt = 0; mt < 2; mt++)
#pragma unroll
        for (int nt = 0; nt < 2; nt++) {
            int c = wn0 + nt * 16 + lm;
#pragma unroll
            for (int i = 0; i < 4; i++) {
                int r = wm0 + mt * 16 + q * 4 + i;
                float v = acc[mt][nt][i] * alpha;
                C[(size_t)(row0 + r) * 768 + col0 + c] = v;
                unsigned short hv, lv;
                split2(v, hv, lv);
                Hi[r][c] = hv; Lo[r][c] = lv;
            }
        }
    __syncthreads();
    int r = tid >> 2, cq = (tid & 3) * 16;
    bs8 vh0, vh1, vl0, vl1;
#pragma unroll
    for (int e = 0; e < 8; e++) {
        vh0[e] = Hi[r][cq + e];     vh1[e] = Hi[r][cq + 8 + e];
        vl0[e] = Lo[r][cq + e];     vl1[e] = Lo[r][cq + 8 + e];
    }
    size_t ro = (size_t)(b * 128 + row0 + r) * 768 + col0 + cq;
    *(bs8*)(nodeh + ro) = vh0; *(bs8*)(nodeh + ro + 8) = vh1;
    *(bs8*)(nodel + ro) = vl0; *(bs8*)(nodel + ro + 8) = vl1;
}

// ---------------------------------------------------------------------------
// Fused graph-sum + batch-norm. grid 12, block 512. (validated round 4)
// ---------------------------------------------------------------------------
__global__ __launch_bounds__(512) void gsum_bnorm_k(
    const float* __restrict__ node, const float* __restrict__ gamma,
    const float* __restrict__ beta, float* __restrict__ out)
{
    __shared__ float gbuf[8][64];
    __shared__ float mean_s[64], inv_s[64];
    int tid = threadIdx.x;
    int bg = tid >> 6, dl = tid & 63;
    int d = blockIdx.x * 64 + dl;
    float v = 0.f;
    for (int i = 0; i < 128; i++)
        v += node[(size_t)(bg * 128 + i) * 768 + d];
    gbuf[bg][dl] = v;
    __syncthreads();
    if (tid < 64) {
        float m = 0.f;
#pragma unroll
        for (int b = 0; b < 8; b++) m += gbuf[b][tid];
        m *= 0.125f;
        float var = 0.f;
#pragma unroll
        for (int b = 0; b < 8; b++) { float t = gbuf[b][tid] - m; var += t * t; }
        var *= 0.125f;
        mean_s[tid] = m;
        inv_s[tid] = 1.0f / sqrtf(var + EPS_V);
    }
    __syncthreads();
    out[bg * 768 + d] = gamma[d] * (v - mean_s[dl]) * inv_s[dl] + beta[d];
}

// ---------------------------------------------------------------------------
extern "C" void kernel_launch(void* const* d_in, const int* in_sizes, int n_in,
                              void* d_out, int out_size, void* d_ws, size_t ws_size,
                              hipStream_t stream)
{
    const float* feature = (const float*)d_in[0];
    // d_in[1] = aspect: unused by the reference
    const int*   adj     = (const int*)d_in[2];
    const float* W0      = (const float*)d_in[3];
    const float* b0      = (const float*)d_in[4];
    const float* W1      = (const float*)d_in[5];
    const float* b1      = (const float*)d_in[6];
    const float* A1      = (const float*)d_in[7];
    const float* ab1     = (const float*)d_in[8];
    const float* A2      = (const float*)d_in[9];
    const float* ab2     = (const float*)d_in[10];
    const float* gamma   = (const float*)d_in[11];
    const float* beta    = (const float*)d_in[12];

    float* ws    = (float*)d_ws;
    float* s     = ws;               // 131072
    float* psum  = ws + 131072;      // 256
    float* bA    = ws + 131328;      // 256
    unsigned short* u = (unsigned short*)(ws + 131584);  // 16B-aligned
    unsigned short* Wt0h = u;                    // 589824 each
    unsigned short* Wt0l = Wt0h + 589824;
    unsigned short* Wt1h = Wt0l + 589824;
    unsigned short* Wt1l = Wt1h + 589824;
    unsigned short* WAth = Wt1l + 589824;        // 196608 each (2 layers)
    unsigned short* WAtl = WAth + 196608;
    unsigned short* fh   = WAtl + 196608;        // 786432 each from here
    unsigned short* fl   = fh + 786432;
    unsigned short* hth  = fl + 786432;
    unsigned short* htl  = hth + 786432;
    unsigned short* ndh  = htl + 786432;
    unsigned short* ndl  = ndh + 786432;
    unsigned short* ph   = ndl + 786432;         // 131072 each
    unsigned short* pl   = ph + 131072;

    float* out       = (float*)d_out;
    float* graph_out = out;          // (8,768)
    float* node_out  = out + 6144;   // (8,128,768)

    prep_k<<<530, 256, 0, stream>>>(W0, W1, A1, feature, b0, b1,
                                    Wt0h, Wt0l, Wt1h, Wt1l,
                                    fh, fl, WAth, WAtl, bA);

    for (int layer = 0; layer < 2; layer++) {
        const unsigned short* Wth = layer ? Wt1h : Wt0h;
        const unsigned short* Wtl = layer ? Wt1l : Wt0l;
        const float* bb = layer ? b1 : b0;
        const unsigned short* Ahg = layer ? ndh : fh;
        const unsigned short* Alg = layer ? ndl : fl;
        gemm_fused_k<<<dim3(14, 16), 256, 0, stream>>>(
            Ahg, Alg, Wth, Wtl, WAth + (size_t)layer * 98304,
            WAtl + (size_t)layer * 98304, bb, hth, htl, s);
        score_k<<<dim3(32, 8), 256, 0, stream>>>(s, adj, ab1, A2, ab2,
                                                 bA + layer * 128, ph, pl, psum);
        attn_mfma_k<<<dim3(12, 2, 8), 256, 0, stream>>>(ph, pl, hth, htl, psum,
                                                        node_out, ndh, ndl);
    }
    gsum_bnorm_k<<<12, 512, 0, stream>>>(node_out, gamma, beta, graph_out);
}